// Round 8
// baseline (134080.334 us; speedup 1.0000x reference)
//
#include <hip/hip_runtime.h>
#include <cstdint>
#include <cfloat>
#include <cmath>

#define NB 64
#define LL 2048
#define HH 512
#define VV 34
#define TT 600
#define GRID 256
#define BLKT 512

typedef unsigned long long ull;

// JAX threefry_partitionable (default since jax 0.4.36): bits = o0 ^ o1. VERIFIED round 2.
#define PARTITIONABLE 1

// Coherence-point (cross-XCD) data path: bypasses L1/L2; memory-side always fresh.
#define LDC(p)    __hip_atomic_load((p), __ATOMIC_RELAXED, __HIP_MEMORY_SCOPE_AGENT)
#define STC(p,v)  __hip_atomic_store((p), (v), __ATOMIC_RELAXED, __HIP_MEMORY_SCOPE_AGENT)

__device__ __forceinline__ ull rtclk(){ return __builtin_amdgcn_s_memrealtime(); }

__device__ __forceinline__ float sigm_(float x){ return 1.0f/(1.0f+expf(-x)); }
__device__ __forceinline__ unsigned rotl_(unsigned x, int r){ return (x<<r)|(x>>(32-r)); }

// Threefry-2x32, 20 rounds, exactly JAX's schedule.
__device__ __forceinline__ void tf2x32_(unsigned k0, unsigned k1, unsigned x0, unsigned x1,
                                        unsigned &o0, unsigned &o1){
  unsigned ks2 = k0 ^ k1 ^ 0x1BD11BDAu;
  x0 += k0; x1 += k1;
  x0+=x1; x1=rotl_(x1,13); x1^=x0;
  x0+=x1; x1=rotl_(x1,15); x1^=x0;
  x0+=x1; x1=rotl_(x1,26); x1^=x0;
  x0+=x1; x1=rotl_(x1, 6); x1^=x0;
  x0+=k1; x1+=ks2+1u;
  x0+=x1; x1=rotl_(x1,17); x1^=x0;
  x0+=x1; x1=rotl_(x1,29); x1^=x0;
  x0+=x1; x1=rotl_(x1,16); x1^=x0;
  x0+=x1; x1=rotl_(x1,24); x1^=x0;
  x0+=ks2; x1+=k0+2u;
  x0+=x1; x1=rotl_(x1,13); x1^=x0;
  x0+=x1; x1=rotl_(x1,15); x1^=x0;
  x0+=x1; x1=rotl_(x1,26); x1^=x0;
  x0+=x1; x1=rotl_(x1, 6); x1^=x0;
  x0+=k0; x1+=k1+3u;
  x0+=x1; x1=rotl_(x1,17); x1^=x0;
  x0+=x1; x1=rotl_(x1,29); x1^=x0;
  x0+=x1; x1=rotl_(x1,16); x1^=x0;
  x0+=x1; x1=rotl_(x1,24); x1^=x0;
  x0+=k1; x1+=ks2+4u;
  x0+=x1; x1=rotl_(x1,13); x1^=x0;
  x0+=x1; x1=rotl_(x1,15); x1^=x0;
  x0+=x1; x1=rotl_(x1,26); x1^=x0;
  x0+=x1; x1=rotl_(x1, 6); x1^=x0;
  x0+=ks2; x1+=k0+5u;
  o0 = x0; o1 = x1;
}

// Marker: spins value/16 realtime ticks so rocprof dur_us*16 decodes the value.
__global__ void k_marker(const ull* __restrict__ src, int idx){
  ull target = src[idx] >> 4;
  ull t0 = rtclk();
  while (rtclk() - t0 < target)
    __builtin_amdgcn_s_sleep(16);
}

__global__ __launch_bounds__(BLKT, 2) void speller_kernel(
    const float* __restrict__ seq, const int* __restrict__ slen,
    const float* __restrict__ Ech, const float* __restrict__ Wkey,
    const float* __restrict__ Wval, const float* __restrict__ bval,
    const float* __restrict__ Wih, const float* __restrict__ Whh,
    const float* __restrict__ bih, const float* __restrict__ bhh,
    const float* __restrict__ Wcdn, const float* __restrict__ bcdn,
    int* __restrict__ out, float* __restrict__ ws, int MS, int CH)
{
  const int tid = threadIdx.x;
  const int bid = blockIdx.x;
  const int gid = bid*BLKT + tid;

  // ---- workspace layout ----
  float* biasf = ws;                         // [2048]  b_ih + b_hh
  float* h0    = biasf + 2048;               // [NB*HH]  coherent
  float* h1    = h0 + NB*HH;                 // [NB*HH]
  float* cb    = h1 + NB*HH;                 // [NB*HH]  coherent (block-private)
  float* ctx   = cb + NB*HH;                 // [NB*HH]  coherent
  float* pm    = ctx + NB*HH;                // [NB*MS]  coherent
  float* ps    = pm + NB*MS;                 // [NB*MS]  coherent
  float* pacc  = ps + NB*MS;                 // [NB*MS*HH] coherent
  int*   iw    = (int*)(pacc + (size_t)NB*MS*HH);
  int*   yv    = iw;                          // [64]    coherent
  int*   pref  = iw + 64;                     // [65]    cached, write-once
  int*   bar   = iw + 192;                    // barrier area (memset 0 per launch)
  ull*   tarea = (ull*)(iw + 768);            // [0..4] markers, [8+bid] per-block C totals

  __shared__ float sXs[128*65];
  __shared__ float sRed[8*8*64];
  __shared__ float sGate[8*64];
  __shared__ float sAcc[8*512];
  __shared__ float sQt[512];
  __shared__ float sHb[512];
  __shared__ float sWm[8], sWs[8], sWf[8];
  __shared__ float sEb[512];
  __shared__ float sHs[512];
  __shared__ float sCt[512];
  __shared__ float sP[34*8];
  __shared__ float sZ[34];
  __shared__ float sAm[32], sAs[32], sAf[32];
  __shared__ float sSc[2];
  __shared__ int   sPref[65];
  __shared__ int   sLenA[64];
  __shared__ int   sYv[64];

  // ---- timing accumulators (tid0 only; cold path) ----
  ull tkstart = 0, lastExit = 0, wA = 0, barAcc = 0, cTot = 0;
  if (tid == 0) tkstart = rtclk();

  // ---- hierarchical grid barrier (R6-verified), with block0 timing ----
  int epoch = 0;
  auto gsync = [&](int mode, int pid){
    __syncthreads();
    epoch++;
    if (tid == 0){
      ull t_arr = (bid == 0) ? rtclk() : 0;
      if (bid == 0 && pid == 0) wA += t_arr - lastExit;
      if (mode == 1) __threadfence();
      const int g = bid >> 5;      // 8 groups of 32 blocks
      int r = __hip_atomic_fetch_add(&bar[32+g*32], 1, __ATOMIC_RELAXED, __HIP_MEMORY_SCOPE_AGENT);
      if (r == epoch*32 - 1){
        int rr = __hip_atomic_fetch_add(&bar[0], 1, __ATOMIC_RELAXED, __HIP_MEMORY_SCOPE_AGENT);
        if (rr == epoch*8 - 1){
          #pragma unroll
          for (int i=0;i<8;i++)
            __hip_atomic_store(&bar[288+i*32], epoch, __ATOMIC_RELAXED, __HIP_MEMORY_SCOPE_AGENT);
        } else {
          while (__hip_atomic_load(&bar[288+g*32], __ATOMIC_RELAXED, __HIP_MEMORY_SCOPE_AGENT) < epoch)
            __builtin_amdgcn_s_sleep(1);
        }
      } else {
        while (__hip_atomic_load(&bar[288+g*32], __ATOMIC_RELAXED, __HIP_MEMORY_SCOPE_AGENT) < epoch)
          __builtin_amdgcn_s_sleep(1);
      }
      if (mode == 1) __threadfence();
      if (bid == 0){
        ull t_ex = rtclk();
        if (pid >= 0) barAcc += t_ex - t_arr;
        lastExit = t_ex;
      }
    }
    __syncthreads();
  };

  // ================= P0: one-time precompute =================
  {
    if (gid < NB*HH){ h0[gid]=0.f; h1[gid]=0.f; cb[gid]=0.f; }
    if (gid < NB) yv[gid] = 0;  // SOS
    if (gid < 2048) biasf[gid] = bih[gid] + bhh[gid];
    if (gid == 0){
      int acc = 0; pref[0] = 0;
      for (int b=0;b<NB;b++){
        int ln = slen[b]; if (ln < 1) ln = 1; if (ln > LL) ln = LL;
        acc += (ln + CH - 1)/CH;
        pref[b+1] = acc;
      }
    }
  }

  // ================= phase lambdas (arithmetic identical to verified R2-R6) =================

  // A: gates = Wih*[emb(y); ctx] + Whh*h + biasf ; LSTM update -> c, hw
  auto phaseA = [&](const float* hr, float* hw){
    const int k0 = bid*2;
    const int w = tid >> 6, lane = tid & 63;
    if (tid < 64) sYv[tid] = LDC(&yv[tid]);
    float acc[8];
    #pragma unroll
    for (int jj=0;jj<8;jj++) acc[jj]=0.f;
    for (int kt=0; kt<12; kt++){
      __syncthreads();
      #pragma unroll
      for (int r=0;r<16;r++){
        int e = r*512 + tid;
        int b = e >> 7, kk = e & 127;
        int mm = kt*128 + kk;
        float v;
        if (kt < 4)      v = Ech[(size_t)sYv[b]*HH + mm];
        else if (kt < 8) v = LDC(&ctx[b*HH + (mm-512)]);
        else             v = LDC(&hr[b*HH + (mm-1024)]);
        sXs[kk*65 + b] = v;
      }
      __syncthreads();
      const float* wrow[8];
      #pragma unroll
      for (int jj=0;jj<8;jj++){
        int j = (jj>>1)*512 + k0 + (jj&1);
        if (kt < 8) wrow[jj] = Wih + (size_t)j*1024 + kt*128;
        else        wrow[jj] = Whh + (size_t)j*512  + (kt-8)*128;
      }
      #pragma unroll
      for (int it=0; it<4; it++){
        int kkb = w*16 + it*4;
        float x0 = sXs[(kkb+0)*65 + lane];
        float x1 = sXs[(kkb+1)*65 + lane];
        float x2 = sXs[(kkb+2)*65 + lane];
        float x3 = sXs[(kkb+3)*65 + lane];
        #pragma unroll
        for (int jj=0;jj<8;jj++){
          float4 wv = *(const float4*)(wrow[jj] + kkb);
          acc[jj] += wv.x*x0; acc[jj] += wv.y*x1;
          acc[jj] += wv.z*x2; acc[jj] += wv.w*x3;
        }
      }
    }
    __syncthreads();
    #pragma unroll
    for (int jj=0;jj<8;jj++) sRed[(w*8+jj)*64 + lane] = acc[jj];
    __syncthreads();
    {
      int jj2 = tid >> 6, b2 = tid & 63;
      int j = (jj2>>1)*512 + k0 + (jj2&1);
      float g = biasf[j];
      #pragma unroll
      for (int w2=0; w2<8; w2++) g += sRed[(w2*8+jj2)*64 + b2];
      sGate[jj2*64 + b2] = g;
    }
    __syncthreads();
    if (tid < 128){
      int k01 = tid >> 6, b3 = tid & 63;
      int k = k0 + k01;
      float gi = sGate[(0+k01)*64 + b3];
      float gf = sGate[(2+k01)*64 + b3];
      float gg = sGate[(4+k01)*64 + b3];
      float go = sGate[(6+k01)*64 + b3];
      float co = LDC(&cb[b3*HH + k]);
      float cn = sigm_(gf)*co + sigm_(gi)*tanhf(gg);
      STC(&cb[b3*HH + k], cn);
      STC(&hw[b3*HH + k], sigm_(go)*tanhf(cn));
    }
  };

  // C: static chunk range per block; per-batch qt recompute; streaming online-softmax
  auto phaseC = [&](const float* hr){
    if (tid < 65) sPref[tid] = pref[tid];
    if (tid < 64){ int ln = slen[tid]; if(ln<1)ln=1; if(ln>LL)ln=LL; sLenA[tid]=ln; }
    __syncthreads();
    const int nTot = sPref[64];
    const int w = tid >> 6, lane = tid & 63;
    const float SCALE = 1.0f / sqrtf(512.0f);
    const int start = (bid*nTot)/GRID, end = ((bid+1)*nTot)/GRID;
    int b = 0, bLast = -1;
    for (int c = start; c < end; ++c){
      while (sPref[b+1] <= c) b++;
      int slot = c - sPref[b];
      int l0 = slot * CH;
      int lend = min(l0 + CH, sLenA[b]);
      if (b != bLast){
        __syncthreads();
        sHb[tid] = LDC(&hr[b*HH + tid]);      // stage h[b] once (coherent)
        __syncthreads();
        float a0 = 0.f;
        for (int k=0;k<512;k++)
          a0 += Wkey[(size_t)k*512 + tid] * sHb[k];
        sQt[tid] = a0;
        bLast = b;
      }
      __syncthreads();   // sQt visible; protects sAcc/sWf reuse across chunks
      const float4* qp = (const float4*)sQt;
      float4 qa = qp[lane], qb = qp[64+lane];
      float m = -FLT_MAX, ss = 0.f;
      float4 aA = make_float4(0,0,0,0), aB = make_float4(0,0,0,0);
      int l = l0 + w;
      float4 ea, eb;
      if (l < lend){
        const float4* rp = (const float4*)(seq + ((size_t)b*LL + l)*HH);
        ea = rp[lane]; eb = rp[64+lane];
      }
      while (l < lend){
        int ln2 = l + 8;
        float4 na, nb;
        if (ln2 < lend){   // 1-deep prefetch (no arithmetic reorder)
          const float4* rp2 = (const float4*)(seq + ((size_t)b*LL + ln2)*HH);
          na = rp2[lane]; nb = rp2[64+lane];
        }
        float d = ea.x*qa.x + ea.y*qa.y + ea.z*qa.z + ea.w*qa.w
                + eb.x*qb.x + eb.y*qb.y + eb.z*qb.z + eb.w*qb.w;
        #pragma unroll
        for (int msk=1; msk<64; msk<<=1) d += __shfl_xor(d, msk, 64);
        float sc = d * SCALE;
        float mn = fmaxf(m, sc);
        float r1 = expf(m - mn);
        float w1 = expf(sc - mn);
        ss = ss*r1 + w1;
        aA.x = aA.x*r1 + w1*ea.x; aA.y = aA.y*r1 + w1*ea.y;
        aA.z = aA.z*r1 + w1*ea.z; aA.w = aA.w*r1 + w1*ea.w;
        aB.x = aB.x*r1 + w1*eb.x; aB.y = aB.y*r1 + w1*eb.y;
        aB.z = aB.z*r1 + w1*eb.z; aB.w = aB.w*r1 + w1*eb.w;
        m = mn;
        ea = na; eb = nb; l = ln2;
      }
      ((float4*)(sAcc + w*512))[lane]    = aA;
      ((float4*)(sAcc + w*512))[64+lane] = aB;
      if (lane == 0){ sWm[w] = m; sWs[w] = ss; }
      __syncthreads();
      if (tid == 0){
        float M = sWm[0];
        #pragma unroll
        for (int i=1;i<8;i++) M = fmaxf(M, sWm[i]);
        float S = 0.f;
        #pragma unroll
        for (int i=0;i<8;i++){ float f = expf(sWm[i]-M); sWf[i]=f; S += sWs[i]*f; }
        STC(&pm[b*MS+slot], M); STC(&ps[b*MS+slot], S);
      }
      __syncthreads();
      {
        float v = 0.f;
        #pragma unroll
        for (int i=0;i<8;i++) v += sAcc[i*512 + tid] * sWf[i];
        STC(&pacc[((size_t)(b*MS+slot))*HH + tid], v);
      }
    }
  };

  // D: reduce -> ebar -> ctx ; logits ; gumbel sample
  auto phaseD = [&](int t, const float* hw){
    if (bid < 64){
      const int b = bid;
      const int nsl = pref[b+1] - pref[b];
      if (tid < nsl){ sAm[tid] = LDC(&pm[b*MS + tid]); sAs[tid] = LDC(&ps[b*MS + tid]); }
      __syncthreads();
      if (tid == 0){
        float M = sAm[0];
        for (int s=1;s<nsl;s++) M = fmaxf(M, sAm[s]);
        float S = 0.f;
        for (int s=0;s<nsl;s++){ float f = expf(sAm[s]-M); sAf[s] = f; S += sAs[s]*f; }
        sSc[0] = S;
      }
      __syncthreads();
      {
        float S = sSc[0];
        float v = 0.f;
        #pragma unroll 4
        for (int s=0;s<nsl;s++) v += LDC(&pacc[((size_t)(b*MS+s))*HH + tid]) * sAf[s];
        sEb[tid] = v / S;
        sHs[tid] = LDC(&hw[b*HH + tid]);
      }
      __syncthreads();
      {
        const float4* wr = (const float4*)(Wval + (size_t)tid*HH);
        const float4* er = (const float4*)sEb;
        float a = bval[tid];
        #pragma unroll 4
        for (int i=0;i<HH/4;i++){
          float4 w4 = wr[i], e4 = er[i];
          a += w4.x*e4.x; a += w4.y*e4.y; a += w4.z*e4.z; a += w4.w*e4.w;
        }
        sCt[tid] = a;
        STC(&ctx[b*HH + tid], a);
      }
      __syncthreads();
      if (t >= 0){
        if (tid < 34*8){
          int v = tid >> 3, ks = tid & 7;
          const float* wr = Wcdn + (size_t)v*1024 + ks*128;
          const float* xr = (ks < 4) ? (sHs + ks*128) : (sCt + (ks-4)*128);
          float p = 0.f;
          for (int i=0;i<128;i++) p += wr[i]*xr[i];
          sP[v*8+ks] = p;
        }
        __syncthreads();
        if (tid < 34){
          float lg = bcdn[tid];
          #pragma unroll
          for (int i=0;i<8;i++) lg += sP[tid*8+i];
          unsigned kk0, kk1; tf2x32_(0u, 42u, 0u, (unsigned)t, kk0, kk1);
          int idx = b*34 + tid;
          unsigned o0, o1, bits;
#if PARTITIONABLE
          tf2x32_(kk0, kk1, 0u, (unsigned)idx, o0, o1);
          bits = o0 ^ o1;
#else
          if (idx < 1088){ tf2x32_(kk0, kk1, (unsigned)idx, (unsigned)(idx+1088), o0, o1); bits = o0; }
          else           { tf2x32_(kk0, kk1, (unsigned)(idx-1088), (unsigned)idx, o0, o1); bits = o1; }
#endif
          float f = __uint_as_float((bits>>9) | 0x3f800000u) - 1.0f;
          float u = fmaxf(f, 1.17549435e-38f);
          float gmb = -logf(-logf(u));
          sZ[tid] = lg + gmb;
        }
        __syncthreads();
        if (tid == 0){
          float best = sZ[0]; int bi = 0;
          for (int v2=1; v2<34; v2++){ if (sZ[v2] > best){ best = sZ[v2]; bi = v2; } }
          STC(&yv[b], bi);
          STC(&out[b*TT + t], bi);
        }
      }
    }
  };

  // ================= schedule: 3 barriers per step =================
  gsync(1, -1);             // full: flush P0 init
  phaseC(h0);               // h0 == 0 -> qt == 0 bit-exactly -> uniform weights
  gsync(0, -1);
  phaseD(-1, h0);           // ebar/ctx only, no sampling
  gsync(0, -1);
  for (int t = 0; t < TT; t++){
    const float* hr = (t & 1) ? h1 : h0;
    float* hwv      = (t & 1) ? h0 : h1;
    phaseA(hr, hwv);
    gsync(0, 0);            // pid 0: attribute interval since last exit to A
    {
      ull c0 = (tid == 0) ? rtclk() : 0;
      phaseC(hwv);
      if (tid == 0) cTot += rtclk() - c0;
    }
    gsync(0, 1);
    phaseD(t, hwv);
    gsync(0, 2);
  }

  // ---- publish timing: per-block C totals, then block0 reduces + writes markers ----
  if (tid == 0)
    __hip_atomic_store(&tarea[8+bid], cTot, __ATOMIC_RELAXED, __HIP_MEMORY_SCOPE_AGENT);
  gsync(0, -1);
  if (bid == 0 && tid == 0){
    ull mx = 0;
    for (int i=0;i<GRID;i++){
      ull v = __hip_atomic_load(&tarea[8+i], __ATOMIC_RELAXED, __HIP_MEMORY_SCOPE_AGENT);
      if (v > mx) mx = v;
    }
    tarea[0] = rtclk() - tkstart;   // m0: total kernel ticks
    tarea[1] = wA;                  // m1: block0 phaseA work
    tarea[2] = cTot;                // m2: block0 phaseC work
    tarea[3] = barAcc;              // m3: block0 total barrier wait
    tarea[4] = mx;                  // m4: max-over-blocks phaseC work
  }
}

extern "C" void kernel_launch(void* const* d_in, const int* in_sizes, int n_in,
                              void* d_out, int out_size, void* d_ws, size_t ws_size,
                              hipStream_t stream)
{
  const float* seq  = (const float*)d_in[0];
  const int*   slen = (const int*)d_in[1];
  const float* Ech  = (const float*)d_in[2];
  const float* Wkey = (const float*)d_in[3];
  // d_in[4] = b_key: cancels inside softmax, unused.
  const float* Wval = (const float*)d_in[5];
  const float* bval = (const float*)d_in[6];
  const float* Wih  = (const float*)d_in[7];
  const float* Whh  = (const float*)d_in[8];
  const float* bih  = (const float*)d_in[9];
  const float* bhh  = (const float*)d_in[10];
  const float* Wcdn = (const float*)d_in[11];
  const float* bcdn = (const float*)d_in[12];
  int*   out = (int*)d_out;
  float* ws  = (float*)d_ws;

  int MS = 32;
  size_t floats_total;
  while (true){
    floats_total = 2048 + 4*(size_t)NB*HH + (size_t)NB*MS*(2 + HH);
    size_t need = (floats_total + 768)*4 + (8 + GRID)*8 + 4096;
    if (need <= ws_size || MS == 1) break;
    MS >>= 1;
  }
  int CH = 2048 / MS;

  // zero the barrier area: ints at iw[192 .. 768)
  size_t bar_off = (floats_total + 192)*4;
  hipMemsetAsync((char*)d_ws + bar_off, 0, 576*4, stream);

  void* args[] = { (void*)&seq, (void*)&slen, (void*)&Ech, (void*)&Wkey,
                   (void*)&Wval, (void*)&bval, (void*)&Wih, (void*)&Whh,
                   (void*)&bih, (void*)&bhh, (void*)&Wcdn, (void*)&bcdn,
                   (void*)&out, (void*)&ws, (void*)&MS, (void*)&CH };
  hipLaunchCooperativeKernel((void*)speller_kernel, dim3(GRID), dim3(BLKT),
                             args, 0, stream);

  // timing markers: dur_us * 16 decodes {total, A, C(blk0), barrier, Cmax}
  const ull* tsrc = (const ull*)((char*)d_ws + (floats_total + 768)*4);
  for (int i = 0; i < 5; i++)
    k_marker<<<1, 64, 0, stream>>>(tsrc, i);
}

// Round 9
// 130505.701 us; speedup vs baseline: 1.0274x; 1.0274x over previous
//
#include <hip/hip_runtime.h>
#include <cstdint>
#include <cfloat>
#include <cmath>

#define NB 64
#define LL 2048
#define HH 512
#define VV 34
#define TT 600
#define GRID 256
#define BLKT 512

// JAX threefry_partitionable (default since jax 0.4.36): bits = o0 ^ o1. VERIFIED round 2.
#define PARTITIONABLE 1

// Coherence-point (cross-XCD) data path: bypasses L1/L2; memory-side always fresh.
#define LDC(p)    __hip_atomic_load((p), __ATOMIC_RELAXED, __HIP_MEMORY_SCOPE_AGENT)
#define STC(p,v)  __hip_atomic_store((p), (v), __ATOMIC_RELAXED, __HIP_MEMORY_SCOPE_AGENT)

__device__ __forceinline__ float sigm_(float x){ return 1.0f/(1.0f+expf(-x)); }
__device__ __forceinline__ unsigned rotl_(unsigned x, int r){ return (x<<r)|(x>>(32-r)); }

// Threefry-2x32, 20 rounds, exactly JAX's schedule.
__device__ __forceinline__ void tf2x32_(unsigned k0, unsigned k1, unsigned x0, unsigned x1,
                                        unsigned &o0, unsigned &o1){
  unsigned ks2 = k0 ^ k1 ^ 0x1BD11BDAu;
  x0 += k0; x1 += k1;
  x0+=x1; x1=rotl_(x1,13); x1^=x0;
  x0+=x1; x1=rotl_(x1,15); x1^=x0;
  x0+=x1; x1=rotl_(x1,26); x1^=x0;
  x0+=x1; x1=rotl_(x1, 6); x1^=x0;
  x0+=k1; x1+=ks2+1u;
  x0+=x1; x1=rotl_(x1,17); x1^=x0;
  x0+=x1; x1=rotl_(x1,29); x1^=x0;
  x0+=x1; x1=rotl_(x1,16); x1^=x0;
  x0+=x1; x1=rotl_(x1,24); x1^=x0;
  x0+=ks2; x1+=k0+2u;
  x0+=x1; x1=rotl_(x1,13); x1^=x0;
  x0+=x1; x1=rotl_(x1,15); x1^=x0;
  x0+=x1; x1=rotl_(x1,26); x1^=x0;
  x0+=x1; x1=rotl_(x1, 6); x1^=x0;
  x0+=k0; x1+=k1+3u;
  x0+=x1; x1=rotl_(x1,17); x1^=x0;
  x0+=x1; x1=rotl_(x1,29); x1^=x0;
  x0+=x1; x1=rotl_(x1,16); x1^=x0;
  x0+=x1; x1=rotl_(x1,24); x1^=x0;
  x0+=k1; x1+=ks2+4u;
  x0+=x1; x1=rotl_(x1,13); x1^=x0;
  x0+=x1; x1=rotl_(x1,15); x1^=x0;
  x0+=x1; x1=rotl_(x1,26); x1^=x0;
  x0+=x1; x1=rotl_(x1, 6); x1^=x0;
  x0+=ks2; x1+=k0+5u;
  o0 = x0; o1 = x1;
}

__global__ __launch_bounds__(BLKT, 2) void speller_kernel(
    const float* __restrict__ seq, const int* __restrict__ slen,
    const float* __restrict__ Ech, const float* __restrict__ Wkey,
    const float* __restrict__ Wval, const float* __restrict__ bval,
    const float* __restrict__ Wih, const float* __restrict__ Whh,
    const float* __restrict__ bih, const float* __restrict__ bhh,
    const float* __restrict__ Wcdn, const float* __restrict__ bcdn,
    int* __restrict__ out, float* __restrict__ ws, int MS, int CH)
{
  const int tid = threadIdx.x;
  const int bid = blockIdx.x;
  const int gid = bid*BLKT + tid;

  // ---- workspace layout ----
  float* biasf = ws;                         // [2048]  b_ih + b_hh          (cached, write-once)
  float* h0    = biasf + 2048;               // [NB*HH]  STC-written
  float* h1    = h0 + NB*HH;                 // [NB*HH]
  float* cb    = h1 + NB*HH;                 // [NB*HH]  LDC/STC (block-private)
  float* ctx   = cb + NB*HH;                 // [NB*HH]  STC-written; cached-read in A (post-inv)
  float* qt    = ctx + NB*HH;                // [NB*HH]  STC-written by B; LDC-read by C
  float* pm    = qt + NB*HH;                 // [NB*MS]  coherent
  float* ps    = pm + NB*MS;                 // [NB*MS]  coherent
  float* pacc  = ps + NB*MS;                 // [NB*MS*HH] coherent
  int*   iw    = (int*)(pacc + (size_t)NB*MS*HH);
  int*   yv    = iw;                          // [64]    coherent
  int*   pref  = iw + 64;                     // [65]    cached, write-once
  int*   bar   = iw + 192;                    // barrier area (memset 0 per launch)

  __shared__ float sXs[128*65];
  __shared__ float sRed[8*8*64];
  __shared__ float sGate[8*64];
  __shared__ float sAcc[8*512];
  __shared__ float sQt[512];
  __shared__ float sHb[512];
  __shared__ float sWm[8], sWs[8], sWf[8];
  __shared__ float sEb[512];
  __shared__ float sHs[512];
  __shared__ float sCt[512];
  __shared__ float sP[34*8];
  __shared__ float sZ[34];
  __shared__ float sAm[32], sAs[32], sAf[32];
  __shared__ float sSc[2];
  __shared__ int   sPref[65];
  __shared__ int   sLenA[64];
  __shared__ int   sYv[64];

  // ---- hierarchical grid barrier ----
  // mode 0: plain flag barrier; mode 1: full fences (one-time after P0);
  // mode 2: acquire-invalidate after completion (buffer_inv only) — before phaseA.
  int epoch = 0;
  auto gsync = [&](int mode){
    __syncthreads();
    epoch++;
    if (tid == 0){
      if (mode == 1) __threadfence();
      const int g = bid >> 5;      // 8 groups of 32 blocks
      int r = __hip_atomic_fetch_add(&bar[32+g*32], 1, __ATOMIC_RELAXED, __HIP_MEMORY_SCOPE_AGENT);
      if (r == epoch*32 - 1){
        int rr = __hip_atomic_fetch_add(&bar[0], 1, __ATOMIC_RELAXED, __HIP_MEMORY_SCOPE_AGENT);
        if (rr == epoch*8 - 1){
          #pragma unroll
          for (int i=0;i<8;i++)
            __hip_atomic_store(&bar[288+i*32], epoch, __ATOMIC_RELAXED, __HIP_MEMORY_SCOPE_AGENT);
        } else {
          while (__hip_atomic_load(&bar[288+g*32], __ATOMIC_RELAXED, __HIP_MEMORY_SCOPE_AGENT) < epoch)
            __builtin_amdgcn_s_sleep(1);
        }
      } else {
        while (__hip_atomic_load(&bar[288+g*32], __ATOMIC_RELAXED, __HIP_MEMORY_SCOPE_AGENT) < epoch)
          __builtin_amdgcn_s_sleep(1);
      }
      if (mode == 1) __threadfence();
    }
    __syncthreads();
    if (mode == 2)   // invalidate stale clean lines; memory-side is fresh (STC writers)
      __builtin_amdgcn_fence(__ATOMIC_ACQUIRE, "agent");
  };

  // ================= P0: one-time precompute =================
  {
    if (gid < NB*HH){ h0[gid]=0.f; h1[gid]=0.f; cb[gid]=0.f; qt[gid]=0.f; }
    if (gid < NB) yv[gid] = 0;  // SOS
    if (gid < 2048) biasf[gid] = bih[gid] + bhh[gid];
    if (gid == 0){
      int acc = 0; pref[0] = 0;
      for (int b=0;b<NB;b++){
        int ln = slen[b]; if (ln < 1) ln = 1; if (ln > LL) ln = LL;
        acc += (ln + CH - 1)/CH;
        pref[b+1] = acc;
      }
    }
  }

  // ================= phase lambdas (arithmetic identical to verified R2-R7) =================

  // A: gates = Wih*[emb(y); ctx] + Whh*h + biasf ; LSTM update -> c, hw
  // ctx/hr read CACHED (fresh after mode-2 inv; L2 amplifies the broadcast).
  auto phaseA = [&](const float* hr, float* hw){
    const int k0 = bid*2;
    const int w = tid >> 6, lane = tid & 63;
    if (tid < 64) sYv[tid] = LDC(&yv[tid]);
    float acc[8];
    #pragma unroll
    for (int jj=0;jj<8;jj++) acc[jj]=0.f;
    for (int kt=0; kt<12; kt++){
      __syncthreads();
      #pragma unroll
      for (int r=0;r<16;r++){
        int e = r*512 + tid;
        int b = e >> 7, kk = e & 127;
        int mm = kt*128 + kk;
        float v;
        if (kt < 4)      v = Ech[(size_t)sYv[b]*HH + mm];
        else if (kt < 8) v = ctx[b*HH + (mm-512)];
        else             v = hr[b*HH + (mm-1024)];
        sXs[kk*65 + b] = v;
      }
      __syncthreads();
      const float* wrow[8];
      #pragma unroll
      for (int jj=0;jj<8;jj++){
        int j = (jj>>1)*512 + k0 + (jj&1);
        if (kt < 8) wrow[jj] = Wih + (size_t)j*1024 + kt*128;
        else        wrow[jj] = Whh + (size_t)j*512  + (kt-8)*128;
      }
      #pragma unroll
      for (int it=0; it<4; it++){
        int kkb = w*16 + it*4;
        float x0 = sXs[(kkb+0)*65 + lane];
        float x1 = sXs[(kkb+1)*65 + lane];
        float x2 = sXs[(kkb+2)*65 + lane];
        float x3 = sXs[(kkb+3)*65 + lane];
        #pragma unroll
        for (int jj=0;jj<8;jj++){
          float4 wv = *(const float4*)(wrow[jj] + kkb);
          acc[jj] += wv.x*x0; acc[jj] += wv.y*x1;
          acc[jj] += wv.z*x2; acc[jj] += wv.w*x3;
        }
      }
    }
    __syncthreads();
    #pragma unroll
    for (int jj=0;jj<8;jj++) sRed[(w*8+jj)*64 + lane] = acc[jj];
    __syncthreads();
    {
      int jj2 = tid >> 6, b2 = tid & 63;
      int j = (jj2>>1)*512 + k0 + (jj2&1);
      float g = biasf[j];
      #pragma unroll
      for (int w2=0; w2<8; w2++) g += sRed[(w2*8+jj2)*64 + b2];
      sGate[jj2*64 + b2] = g;
    }
    __syncthreads();
    if (tid < 128){
      int k01 = tid >> 6, b3 = tid & 63;
      int k = k0 + k01;
      float gi = sGate[(0+k01)*64 + b3];
      float gf = sGate[(2+k01)*64 + b3];
      float gg = sGate[(4+k01)*64 + b3];
      float go = sGate[(6+k01)*64 + b3];
      float co = LDC(&cb[b3*HH + k]);
      float cn = sigm_(gf)*co + sigm_(gi)*tanhf(gg);
      STC(&cb[b3*HH + k], cn);
      STC(&hw[b3*HH + k], sigm_(go)*tanhf(cn));
    }
  };

  // B: qt[b][h'] = sum_k Wkey[k][h'] * h[b][k]  — ONCE per step (32 blocks, 2 b each).
  // Same FMA order as the verified R2 k_qt; unroll-8 gives memory ILP on the serial chain.
  auto phaseB = [&](const float* hw){
    if (bid < 32){
      int b0 = bid*2, b1 = b0+1;
      sHb[tid] = LDC(&hw[b0*HH + tid]);
      sHs[tid] = LDC(&hw[b1*HH + tid]);
      __syncthreads();
      float a0=0.f, a1=0.f;
      #pragma unroll 8
      for (int k=0;k<512;k++){
        float wv = Wkey[(size_t)k*512 + tid];
        a0 += wv * sHb[k];
        a1 += wv * sHs[k];
      }
      STC(&qt[b0*HH + tid], a0);
      STC(&qt[b1*HH + tid], a1);
    }
  };

  // C: static chunk range per block; qt loaded (not recomputed); 8-deep primed prefetch.
  auto phaseC = [&](){
    if (tid < 65) sPref[tid] = pref[tid];
    if (tid < 64){ int ln = slen[tid]; if(ln<1)ln=1; if(ln>LL)ln=LL; sLenA[tid]=ln; }
    __syncthreads();
    const int nTot = sPref[64];
    const int w = tid >> 6, lane = tid & 63;
    const float SCALE = 1.0f / sqrtf(512.0f);
    const int start = (bid*nTot)/GRID, end = ((bid+1)*nTot)/GRID;
    int b = 0, bLast = -1;
    for (int c = start; c < end; ++c){
      while (sPref[b+1] <= c) b++;
      int slot = c - sPref[b];
      int l0 = slot * CH;
      int lend = min(l0 + CH, sLenA[b]);
      if (b != bLast){
        __syncthreads();
        sQt[tid] = LDC(&qt[b*HH + tid]);   // 2 KB coherent load, once per batch switch
        bLast = b;
      }
      __syncthreads();   // sQt visible; protects sAcc/sWf reuse across chunks
      const float4* qp = (const float4*)sQt;
      float4 qa = qp[lane], qb = qp[64+lane];
      float m = -FLT_MAX, ss = 0.f;
      float4 aA = make_float4(0,0,0,0), aB = make_float4(0,0,0,0);
      for (int ls = l0; ls < lend; ls += 64){
        float4 ra[8], rb[8];
        #pragma unroll
        for (int d=0; d<8; d++){
          int row = ls + w + d*8;
          if (row < lend){
            const float4* rp = (const float4*)(seq + ((size_t)b*LL + row)*HH);
            ra[d] = rp[lane]; rb[d] = rp[64+lane];
          }
        }
        #pragma unroll
        for (int d=0; d<8; d++){
          int row = ls + w + d*8;
          if (row < lend){
            float4 ea = ra[d], eb = rb[d];
            float dd = ea.x*qa.x + ea.y*qa.y + ea.z*qa.z + ea.w*qa.w
                     + eb.x*qb.x + eb.y*qb.y + eb.z*qb.z + eb.w*qb.w;
            #pragma unroll
            for (int msk=1; msk<64; msk<<=1) dd += __shfl_xor(dd, msk, 64);
            float sc = dd * SCALE;
            float mn = fmaxf(m, sc);
            float r1 = expf(m - mn);
            float w1 = expf(sc - mn);
            ss = ss*r1 + w1;
            aA.x = aA.x*r1 + w1*ea.x; aA.y = aA.y*r1 + w1*ea.y;
            aA.z = aA.z*r1 + w1*ea.z; aA.w = aA.w*r1 + w1*ea.w;
            aB.x = aB.x*r1 + w1*eb.x; aB.y = aB.y*r1 + w1*eb.y;
            aB.z = aB.z*r1 + w1*eb.z; aB.w = aB.w*r1 + w1*eb.w;
            m = mn;
          }
        }
      }
      ((float4*)(sAcc + w*512))[lane]    = aA;
      ((float4*)(sAcc + w*512))[64+lane] = aB;
      if (lane == 0){ sWm[w] = m; sWs[w] = ss; }
      __syncthreads();
      if (tid == 0){
        float M = sWm[0];
        #pragma unroll
        for (int i=1;i<8;i++) M = fmaxf(M, sWm[i]);
        float S = 0.f;
        #pragma unroll
        for (int i=0;i<8;i++){ float f = expf(sWm[i]-M); sWf[i]=f; S += sWs[i]*f; }
        STC(&pm[b*MS+slot], M); STC(&ps[b*MS+slot], S);
      }
      __syncthreads();
      {
        float v = 0.f;
        #pragma unroll
        for (int i=0;i<8;i++) v += sAcc[i*512 + tid] * sWf[i];
        STC(&pacc[((size_t)(b*MS+slot))*HH + tid], v);
      }
    }
  };

  // D: reduce -> ebar -> ctx ; logits ; gumbel sample
  auto phaseD = [&](int t, const float* hw){
    if (bid < 64){
      const int b = bid;
      const int nsl = pref[b+1] - pref[b];
      if (tid < nsl){ sAm[tid] = LDC(&pm[b*MS + tid]); sAs[tid] = LDC(&ps[b*MS + tid]); }
      __syncthreads();
      if (tid == 0){
        float M = sAm[0];
        for (int s=1;s<nsl;s++) M = fmaxf(M, sAm[s]);
        float S = 0.f;
        for (int s=0;s<nsl;s++){ float f = expf(sAm[s]-M); sAf[s] = f; S += sAs[s]*f; }
        sSc[0] = S;
      }
      __syncthreads();
      {
        float S = sSc[0];
        float v = 0.f;
        #pragma unroll 8
        for (int s=0;s<nsl;s++) v += LDC(&pacc[((size_t)(b*MS+s))*HH + tid]) * sAf[s];
        sEb[tid] = v / S;
        sHs[tid] = LDC(&hw[b*HH + tid]);
      }
      __syncthreads();
      {
        const float4* wr = (const float4*)(Wval + (size_t)tid*HH);
        const float4* er = (const float4*)sEb;
        float a = bval[tid];
        #pragma unroll 8
        for (int i=0;i<HH/4;i++){
          float4 w4 = wr[i], e4 = er[i];
          a += w4.x*e4.x; a += w4.y*e4.y; a += w4.z*e4.z; a += w4.w*e4.w;
        }
        sCt[tid] = a;
        STC(&ctx[b*HH + tid], a);
      }
      __syncthreads();
      if (t >= 0){
        if (tid < 34*8){
          int v = tid >> 3, ks = tid & 7;
          const float* wr = Wcdn + (size_t)v*1024 + ks*128;
          const float* xr = (ks < 4) ? (sHs + ks*128) : (sCt + (ks-4)*128);
          float p = 0.f;
          #pragma unroll 8
          for (int i=0;i<128;i++) p += wr[i]*xr[i];
          sP[v*8+ks] = p;
        }
        __syncthreads();
        if (tid < 34){
          float lg = bcdn[tid];
          #pragma unroll
          for (int i=0;i<8;i++) lg += sP[tid*8+i];
          unsigned kk0, kk1; tf2x32_(0u, 42u, 0u, (unsigned)t, kk0, kk1);
          int idx = b*34 + tid;
          unsigned o0, o1, bits;
#if PARTITIONABLE
          tf2x32_(kk0, kk1, 0u, (unsigned)idx, o0, o1);
          bits = o0 ^ o1;
#else
          if (idx < 1088){ tf2x32_(kk0, kk1, (unsigned)idx, (unsigned)(idx+1088), o0, o1); bits = o0; }
          else           { tf2x32_(kk0, kk1, (unsigned)(idx-1088), (unsigned)idx, o0, o1); bits = o1; }
#endif
          float f = __uint_as_float((bits>>9) | 0x3f800000u) - 1.0f;
          float u = fmaxf(f, 1.17549435e-38f);
          float gmb = -logf(-logf(u));
          sZ[tid] = lg + gmb;
        }
        __syncthreads();
        if (tid == 0){
          float best = sZ[0]; int bi = 0;
          for (int v2=1; v2<34; v2++){ if (sZ[v2] > best){ best = sZ[v2]; bi = v2; } }
          STC(&yv[b], bi);
          STC(&out[b*TT + t], bi);
        }
      }
    }
  };

  // ================= schedule: 4 barriers per step (one carries the inv) =================
  gsync(1);                 // full: flush P0 init
  phaseC();                 // qt == 0 (P0) -> uniform weights over valid positions
  gsync(0);
  phaseD(-1, h0);           // ebar/ctx only, no sampling
  gsync(2);                 // inv before first phaseA
  for (int t = 0; t < TT; t++){
    const float* hr = (t & 1) ? h1 : h0;
    float* hwv      = (t & 1) ? h0 : h1;
    phaseA(hr, hwv);
    gsync(0);
    phaseB(hwv);
    gsync(0);
    phaseC();
    gsync(0);
    phaseD(t, hwv);
    gsync(2);               // inv before next step's phaseA
  }
}

extern "C" void kernel_launch(void* const* d_in, const int* in_sizes, int n_in,
                              void* d_out, int out_size, void* d_ws, size_t ws_size,
                              hipStream_t stream)
{
  const float* seq  = (const float*)d_in[0];
  const int*   slen = (const int*)d_in[1];
  const float* Ech  = (const float*)d_in[2];
  const float* Wkey = (const float*)d_in[3];
  // d_in[4] = b_key: cancels inside softmax, unused.
  const float* Wval = (const float*)d_in[5];
  const float* bval = (const float*)d_in[6];
  const float* Wih  = (const float*)d_in[7];
  const float* Whh  = (const float*)d_in[8];
  const float* bih  = (const float*)d_in[9];
  const float* bhh  = (const float*)d_in[10];
  const float* Wcdn = (const float*)d_in[11];
  const float* bcdn = (const float*)d_in[12];
  int*   out = (int*)d_out;
  float* ws  = (float*)d_ws;

  int MS = 32;
  size_t floats_total;
  while (true){
    floats_total = 2048 + 5*(size_t)NB*HH + (size_t)NB*MS*(2 + HH);
    size_t need = (floats_total + 1024)*4;
    if (need <= ws_size || MS == 1) break;
    MS >>= 1;
  }
  int CH = 2048 / MS;

  // zero the barrier area: ints at iw[192 .. 768)
  size_t bar_off = (floats_total + 192)*4;
  hipMemsetAsync((char*)d_ws + bar_off, 0, 576*4, stream);

  void* args[] = { (void*)&seq, (void*)&slen, (void*)&Ech, (void*)&Wkey,
                   (void*)&Wval, (void*)&bval, (void*)&Wih, (void*)&Whh,
                   (void*)&bih, (void*)&bhh, (void*)&Wcdn, (void*)&bcdn,
                   (void*)&out, (void*)&ws, (void*)&MS, (void*)&CH };
  hipLaunchCooperativeKernel((void*)speller_kernel, dim3(GRID), dim3(BLKT),
                             args, 0, stream);
}

// Round 10
// 86115.839 us; speedup vs baseline: 1.5570x; 1.5155x over previous
//
#include <hip/hip_runtime.h>
#include <cstdint>
#include <cfloat>
#include <cmath>

#define NB 64
#define LL 2048
#define HH 512
#define VV 34
#define TT 600
#define GRID 256
#define BLKT 512
#define NGRP 8
#define GBLK 32     // blocks per group

// JAX threefry_partitionable (default since jax 0.4.36): bits = o0 ^ o1. VERIFIED round 2.
#define PARTITIONABLE 1

// Coherence-point (cross-XCD-safe) data path: bypasses L1/L2; no fences needed.
#define LDC(p)    __hip_atomic_load((p), __ATOMIC_RELAXED, __HIP_MEMORY_SCOPE_AGENT)
#define STC(p,v)  __hip_atomic_store((p), (v), __ATOMIC_RELAXED, __HIP_MEMORY_SCOPE_AGENT)

__device__ __forceinline__ float sigm_(float x){ return 1.0f/(1.0f+expf(-x)); }
__device__ __forceinline__ unsigned rotl_(unsigned x, int r){ return (x<<r)|(x>>(32-r)); }

// Threefry-2x32, 20 rounds, exactly JAX's schedule.
__device__ __forceinline__ void tf2x32_(unsigned k0, unsigned k1, unsigned x0, unsigned x1,
                                        unsigned &o0, unsigned &o1){
  unsigned ks2 = k0 ^ k1 ^ 0x1BD11BDAu;
  x0 += k0; x1 += k1;
  x0+=x1; x1=rotl_(x1,13); x1^=x0;
  x0+=x1; x1=rotl_(x1,15); x1^=x0;
  x0+=x1; x1=rotl_(x1,26); x1^=x0;
  x0+=x1; x1=rotl_(x1, 6); x1^=x0;
  x0+=k1; x1+=ks2+1u;
  x0+=x1; x1=rotl_(x1,17); x1^=x0;
  x0+=x1; x1=rotl_(x1,29); x1^=x0;
  x0+=x1; x1=rotl_(x1,16); x1^=x0;
  x0+=x1; x1=rotl_(x1,24); x1^=x0;
  x0+=ks2; x1+=k0+2u;
  x0+=x1; x1=rotl_(x1,13); x1^=x0;
  x0+=x1; x1=rotl_(x1,15); x1^=x0;
  x0+=x1; x1=rotl_(x1,26); x1^=x0;
  x0+=x1; x1=rotl_(x1, 6); x1^=x0;
  x0+=k0; x1+=k1+3u;
  x0+=x1; x1=rotl_(x1,17); x1^=x0;
  x0+=x1; x1=rotl_(x1,29); x1^=x0;
  x0+=x1; x1=rotl_(x1,16); x1^=x0;
  x0+=x1; x1=rotl_(x1,24); x1^=x0;
  x0+=k1; x1+=ks2+4u;
  x0+=x1; x1=rotl_(x1,13); x1^=x0;
  x0+=x1; x1=rotl_(x1,15); x1^=x0;
  x0+=x1; x1=rotl_(x1,26); x1^=x0;
  x0+=x1; x1=rotl_(x1, 6); x1^=x0;
  x0+=ks2; x1+=k0+5u;
  o0 = x0; o1 = x1;
}

__global__ __launch_bounds__(BLKT, 2) void speller_kernel(
    const float* __restrict__ seq, const int* __restrict__ slen,
    const float* __restrict__ Ech, const float* __restrict__ Wkey,
    const float* __restrict__ Wval, const float* __restrict__ bval,
    const float* __restrict__ Wih, const float* __restrict__ Whh,
    const float* __restrict__ bih, const float* __restrict__ bhh,
    const float* __restrict__ Wcdn, const float* __restrict__ bcdn,
    int* __restrict__ out, float* __restrict__ ws, int MS, int CH)
{
  const int tid = threadIdx.x;
  const int bid = blockIdx.x;
  const int grp = bid & 7;         // group ~ XCD (round-robin heuristic; perf-only)
  const int li  = bid >> 3;        // local block index within group, 0..31
  const int gb0 = grp * 8;         // first batch of this group

  // ---- workspace layout (all cross-block state via STC/LDC) ----
  float* h0   = ws;                          // [64][512]
  float* h1   = h0 + NB*HH;
  float* qt   = h1 + NB*HH;
  float* ctx  = qt + NB*HH;
  float* pm   = ctx + NB*HH;                 // [64][MS]
  float* ps   = pm + NB*MS;
  float* pacc = ps + NB*MS;                  // [64][MS][512]
  int*   iw   = (int*)(pacc + (size_t)NB*MS*HH);
  int*   yv   = iw;                          // [64]
  int*   bar  = iw + 64;                     // [8*64] zeroed per launch

  __shared__ float sX[24*516];    // A: [sec(3)*8batches][512 cols], pad 516 (conflict-free)
  __shared__ float sRed[8*8*64];  // A: 8 waves x 8 octs x 64 lanes
  __shared__ float sGate[512];    // A: [64 rows][8 b]
  __shared__ float sAcc[8*512];   // C: per-wave accumulators
  __shared__ float sQt[512];
  __shared__ float sHb[512];      // B staging
  __shared__ float sWm[8], sWs[8], sWf[8];
  __shared__ float sEb[512], sHs[512], sCt[512];
  __shared__ float sP[34*8];
  __shared__ float sZ[34];
  __shared__ float sAm[32], sAs[32], sAf[32];
  __shared__ float sSc[2];
  __shared__ int   sYv[8];
  __shared__ int   sLen[8];
  __shared__ int   sPref[9];

  // c-state lives in registers: threads 0..127 hold c[k'=tid>>3][b=tid&7]
  float creg = 0.f;

  // ---- group-local (32-block) flag barrier; no fences (STC/LDC data path) ----
  int epoch = 0;
  auto gbar = [&](){
    __syncthreads();
    epoch++;
    if (tid == 0){
      int* arr = &bar[grp*64];
      int* rel = &bar[grp*64 + 32];
      int r = __hip_atomic_fetch_add(arr, 1, __ATOMIC_RELAXED, __HIP_MEMORY_SCOPE_AGENT);
      if (r == epoch*GBLK - 1)
        __hip_atomic_store(rel, epoch, __ATOMIC_RELAXED, __HIP_MEMORY_SCOPE_AGENT);
      else
        while (__hip_atomic_load(rel, __ATOMIC_RELAXED, __HIP_MEMORY_SCOPE_AGENT) < epoch)
          __builtin_amdgcn_s_sleep(1);
    }
    __syncthreads();
  };

  // ================= init (per group) =================
  if (li < 8){
    int bb = gb0 + li;
    STC(&h0[bb*HH + tid], 0.f);
    STC(&h1[bb*HH + tid], 0.f);
    STC(&qt[bb*HH + tid], 0.f);
  }
  if (li == 8 && tid < 8) STC(&yv[gb0 + tid], 0);   // SOS

  // ================= phases (bit-exact vs verified R2/R7 kernels) =================

  // A: gates = Wih*[emb(y); ctx] + Whh*h + (bih+bhh) ; LSTM update -> creg, hw
  // Block li owns k' = li*16..li*16+15 (rows j = g*512 + li*16 + k', g=0..3) for 8 batches.
  auto phaseA = [&](const float* hr, float* hw){
    if (tid < 8) sYv[tid] = LDC(&yv[gb0 + tid]);
    __syncthreads();
    #pragma unroll
    for (int i = 0; i < 24; i++){
      int b = i & 7, s = i >> 3;
      float v;
      if (s == 0)      v = Ech[(size_t)sYv[b]*HH + tid];
      else if (s == 1) v = LDC(&ctx[(gb0+b)*HH + tid]);
      else             v = LDC(&hr[(gb0+b)*HH + tid]);
      sX[i*516 + tid] = v;
    }
    __syncthreads();
    const int w = tid >> 6, lane = tid & 63, rr = lane >> 3, bb = lane & 7;
    float acc[8];
    #pragma unroll
    for (int o=0;o<8;o++) acc[o]=0.f;
    for (int kt = 0; kt < 12; kt++){
      const int sec = (kt < 4) ? 0 : (kt < 8) ? 1 : 2;
      const int cb4 = (kt & 3) * 128;
      #pragma unroll
      for (int it = 0; it < 4; it++){
        int kkb = w*16 + it*4;            // same 8-wave k-partition as verified A
        const float* xp = &sX[(sec*8 + bb)*516 + cb4 + kkb];
        float x0 = xp[0], x1 = xp[1], x2 = xp[2], x3 = xp[3];
        #pragma unroll
        for (int o = 0; o < 8; o++){
          int jl = o*8 + rr;
          int j  = (jl >> 4)*512 + li*16 + (jl & 15);
          const float* wp = (kt < 8) ? Wih + (size_t)j*1024 + kt*128 + kkb
                                     : Whh + (size_t)j*512  + (kt-8)*128 + kkb;
          float4 wv = *(const float4*)wp;
          acc[o] += wv.x*x0; acc[o] += wv.y*x1;
          acc[o] += wv.z*x2; acc[o] += wv.w*x3;
        }
      }
    }
    __syncthreads();
    #pragma unroll
    for (int o=0;o<8;o++) sRed[(w*8+o)*64 + lane] = acc[o];
    __syncthreads();
    {
      int jl = tid >> 3, b2 = tid & 7;
      int o = jl >> 3, rr2 = jl & 7;
      int j = (jl >> 4)*512 + li*16 + (jl & 15);
      float g = bih[j] + bhh[j];
      #pragma unroll
      for (int w2 = 0; w2 < 8; w2++) g += sRed[(w2*8+o)*64 + rr2*8 + b2];
      sGate[jl*8 + b2] = g;
    }
    __syncthreads();
    if (tid < 128){
      int kp = tid >> 3, b3 = tid & 7;
      float gi = sGate[(0*16+kp)*8 + b3];
      float gf = sGate[(1*16+kp)*8 + b3];
      float gg = sGate[(2*16+kp)*8 + b3];
      float go = sGate[(3*16+kp)*8 + b3];
      float cn = sigm_(gf)*creg + sigm_(gi)*tanhf(gg);
      creg = cn;
      STC(&hw[(gb0+b3)*HH + li*16 + kp], sigm_(go)*tanhf(cn));
    }
  };

  // B: qt[b][col] = sum_k Wkey[k][col]*h[b][k] — 4 blocks/batch, 128 cols each,
  // single-accumulator k-order identical to verified R2 k_qt.
  auto phaseB = [&](const float* hw){
    int bb = gb0 + (li >> 2);
    int c0 = (li & 3) * 128;
    sHb[tid] = LDC(&hw[bb*HH + tid]);
    __syncthreads();
    if (tid < 128){
      int col = c0 + tid;
      float a0 = 0.f;
      #pragma unroll 8
      for (int k = 0; k < 512; k++)
        a0 += Wkey[(size_t)k*HH + col] * sHb[k];
      STC(&qt[bb*HH + col], a0);
    }
  };

  // C: group-local static chunk ranges; streaming online-softmax, 8-deep primed prefetch
  // (inner loop verbatim from verified R7/R9).
  auto phaseC = [&](){
    if (tid < 8){ int ln = slen[gb0+tid]; if(ln<1)ln=1; if(ln>LL)ln=LL; sLen[tid]=ln; }
    __syncthreads();
    if (tid == 0){
      sPref[0] = 0;
      for (int i=0;i<8;i++) sPref[i+1] = sPref[i] + (sLen[i]+CH-1)/CH;
    }
    __syncthreads();
    const int gTot = sPref[8];
    const int w = tid >> 6, lane = tid & 63;
    const float SCALE = 1.0f / sqrtf(512.0f);
    const int start = (li*gTot)/GBLK, end = ((li+1)*gTot)/GBLK;
    int b = 0, bLast = -1;
    for (int c = start; c < end; ++c){
      while (sPref[b+1] <= c) b++;
      int slot = c - sPref[b];
      int l0 = slot * CH;
      int lend = min(l0 + CH, sLen[b]);
      int bb = gb0 + b;
      if (b != bLast){
        __syncthreads();
        sQt[tid] = LDC(&qt[bb*HH + tid]);
        bLast = b;
      }
      __syncthreads();
      const float4* qp = (const float4*)sQt;
      float4 qa = qp[lane], qb = qp[64+lane];
      float m = -FLT_MAX, ss = 0.f;
      float4 aA = make_float4(0,0,0,0), aB = make_float4(0,0,0,0);
      for (int ls = l0; ls < lend; ls += 64){
        float4 ra[8], rb[8];
        #pragma unroll
        for (int d=0; d<8; d++){
          int row = ls + w + d*8;
          if (row < lend){
            const float4* rp = (const float4*)(seq + ((size_t)bb*LL + row)*HH);
            ra[d] = rp[lane]; rb[d] = rp[64+lane];
          }
        }
        #pragma unroll
        for (int d=0; d<8; d++){
          int row = ls + w + d*8;
          if (row < lend){
            float4 ea = ra[d], eb = rb[d];
            float dd = ea.x*qa.x + ea.y*qa.y + ea.z*qa.z + ea.w*qa.w
                     + eb.x*qb.x + eb.y*qb.y + eb.z*qb.z + eb.w*qb.w;
            #pragma unroll
            for (int msk=1; msk<64; msk<<=1) dd += __shfl_xor(dd, msk, 64);
            float sc = dd * SCALE;
            float mn = fmaxf(m, sc);
            float r1 = expf(m - mn);
            float w1 = expf(sc - mn);
            ss = ss*r1 + w1;
            aA.x = aA.x*r1 + w1*ea.x; aA.y = aA.y*r1 + w1*ea.y;
            aA.z = aA.z*r1 + w1*ea.z; aA.w = aA.w*r1 + w1*ea.w;
            aB.x = aB.x*r1 + w1*eb.x; aB.y = aB.y*r1 + w1*eb.y;
            aB.z = aB.z*r1 + w1*eb.z; aB.w = aB.w*r1 + w1*eb.w;
            m = mn;
          }
        }
      }
      ((float4*)(sAcc + w*512))[lane]    = aA;
      ((float4*)(sAcc + w*512))[64+lane] = aB;
      if (lane == 0){ sWm[w] = m; sWs[w] = ss; }
      __syncthreads();
      if (tid == 0){
        float M = sWm[0];
        #pragma unroll
        for (int i=1;i<8;i++) M = fmaxf(M, sWm[i]);
        float S = 0.f;
        #pragma unroll
        for (int i=0;i<8;i++){ float f = expf(sWm[i]-M); sWf[i]=f; S += sWs[i]*f; }
        STC(&pm[bb*MS+slot], M); STC(&ps[bb*MS+slot], S);
      }
      __syncthreads();
      {
        float v = 0.f;
        #pragma unroll
        for (int i=0;i<8;i++) v += sAcc[i*512 + tid] * sWf[i];
        STC(&pacc[((size_t)(bb*MS+slot))*HH + tid], v);
      }
    }
  };

  // D: reduce -> ebar -> ctx ; logits ; gumbel sample. 1 block per batch (li<8).
  auto phaseD = [&](int t, const float* hw){
    if (li < 8){
      const int bb = gb0 + li;
      int ln = slen[bb]; if(ln<1)ln=1; if(ln>LL)ln=LL;
      const int nsl = (ln + CH - 1)/CH;
      if (tid < nsl){ sAm[tid] = LDC(&pm[bb*MS + tid]); sAs[tid] = LDC(&ps[bb*MS + tid]); }
      __syncthreads();
      if (tid == 0){
        float M = sAm[0];
        for (int s=1;s<nsl;s++) M = fmaxf(M, sAm[s]);
        float S = 0.f;
        for (int s=0;s<nsl;s++){ float f = expf(sAm[s]-M); sAf[s] = f; S += sAs[s]*f; }
        sSc[0] = S;
      }
      __syncthreads();
      {
        float S = sSc[0];
        float v = 0.f;
        #pragma unroll 8
        for (int s=0;s<nsl;s++) v += LDC(&pacc[((size_t)(bb*MS+s))*HH + tid]) * sAf[s];
        sEb[tid] = v / S;
        sHs[tid] = LDC(&hw[bb*HH + tid]);
      }
      __syncthreads();
      {
        const float4* wr = (const float4*)(Wval + (size_t)tid*HH);
        const float4* er = (const float4*)sEb;
        float a = bval[tid];
        #pragma unroll 8
        for (int i=0;i<HH/4;i++){
          float4 w4 = wr[i], e4 = er[i];
          a += w4.x*e4.x; a += w4.y*e4.y; a += w4.z*e4.z; a += w4.w*e4.w;
        }
        sCt[tid] = a;
        STC(&ctx[bb*HH + tid], a);
      }
      __syncthreads();
      if (t >= 0){
        if (tid < 34*8){
          int v = tid >> 3, ks = tid & 7;
          const float* wr = Wcdn + (size_t)v*1024 + ks*128;
          const float* xr = (ks < 4) ? (sHs + ks*128) : (sCt + (ks-4)*128);
          float p = 0.f;
          #pragma unroll 8
          for (int i=0;i<128;i++) p += wr[i]*xr[i];
          sP[v*8+ks] = p;
        }
        __syncthreads();
        if (tid < 34){
          float lg = bcdn[tid];
          #pragma unroll
          for (int i=0;i<8;i++) lg += sP[tid*8+i];
          unsigned kk0, kk1; tf2x32_(0u, 42u, 0u, (unsigned)t, kk0, kk1);
          int idx = bb*34 + tid;
          unsigned o0, o1, bits;
#if PARTITIONABLE
          tf2x32_(kk0, kk1, 0u, (unsigned)idx, o0, o1);
          bits = o0 ^ o1;
#else
          if (idx < 1088){ tf2x32_(kk0, kk1, (unsigned)idx, (unsigned)(idx+1088), o0, o1); bits = o0; }
          else           { tf2x32_(kk0, kk1, (unsigned)(idx-1088), (unsigned)idx, o0, o1); bits = o1; }
#endif
          float f = __uint_as_float((bits>>9) | 0x3f800000u) - 1.0f;
          float u = fmaxf(f, 1.17549435e-38f);
          float gmb = -logf(-logf(u));
          sZ[tid] = lg + gmb;
        }
        __syncthreads();
        if (tid == 0){
          float best = sZ[0]; int bi = 0;
          for (int v2=1; v2<34; v2++){ if (sZ[v2] > best){ best = sZ[v2]; bi = v2; } }
          STC(&yv[bb], bi);
          STC(&out[bb*TT + t], bi);
        }
      }
    }
  };

  // ================= schedule: fully group-local, 4 group barriers per step =================
  gbar();
  phaseC();                 // qt == 0 -> uniform weights over valid positions
  gbar();
  phaseD(-1, h0);           // ebar/ctx only, no sampling
  gbar();
  for (int t = 0; t < TT; t++){
    const float* hr = (t & 1) ? h1 : h0;
    float* hwv      = (t & 1) ? h0 : h1;
    phaseA(hr, hwv);
    gbar();
    phaseB(hwv);
    gbar();
    phaseC();
    gbar();
    phaseD(t, hwv);
    gbar();
  }
}

extern "C" void kernel_launch(void* const* d_in, const int* in_sizes, int n_in,
                              void* d_out, int out_size, void* d_ws, size_t ws_size,
                              hipStream_t stream)
{
  const float* seq  = (const float*)d_in[0];
  const int*   slen = (const int*)d_in[1];
  const float* Ech  = (const float*)d_in[2];
  const float* Wkey = (const float*)d_in[3];
  // d_in[4] = b_key: cancels inside softmax, unused.
  const float* Wval = (const float*)d_in[5];
  const float* bval = (const float*)d_in[6];
  const float* Wih  = (const float*)d_in[7];
  const float* Whh  = (const float*)d_in[8];
  const float* bih  = (const float*)d_in[9];
  const float* bhh  = (const float*)d_in[10];
  const float* Wcdn = (const float*)d_in[11];
  const float* bcdn = (const float*)d_in[12];
  int*   out = (int*)d_out;
  float* ws  = (float*)d_ws;

  int MS = 32;
  size_t floats_total;
  while (true){
    floats_total = 4*(size_t)NB*HH + (size_t)NB*MS*(2 + HH);
    size_t need = (floats_total + 1024)*4;
    if (need <= ws_size || MS == 1) break;
    MS >>= 1;
  }
  int CH = 2048 / MS;

  // zero the barrier area: ints at iw[64 .. 576)
  size_t bar_off = (floats_total + 64)*4;
  hipMemsetAsync((char*)d_ws + bar_off, 0, 512*4, stream);

  void* args[] = { (void*)&seq, (void*)&slen, (void*)&Ech, (void*)&Wkey,
                   (void*)&Wval, (void*)&bval, (void*)&Wih, (void*)&Whh,
                   (void*)&bih, (void*)&bhh, (void*)&Wcdn, (void*)&bcdn,
                   (void*)&out, (void*)&ws, (void*)&MS, (void*)&CH };
  hipLaunchCooperativeKernel((void*)speller_kernel, dim3(GRID), dim3(BLKT),
                             args, 0, stream);
}

// Round 11
// 82682.733 us; speedup vs baseline: 1.6216x; 1.0415x over previous
//
#include <hip/hip_runtime.h>
#include <cstdint>
#include <cfloat>
#include <cmath>

#define NB 64
#define LL 2048
#define HH 512
#define VV 34
#define TT 600
#define BLKT 512
#define NGRP 8

// JAX threefry_partitionable (default since jax 0.4.36): bits = o0 ^ o1. VERIFIED round 2.
#define PARTITIONABLE 1

// Coherence-point (cross-XCD-safe) data path: bypasses L1/L2; no fences needed.
#define LDC(p)    __hip_atomic_load((p), __ATOMIC_RELAXED, __HIP_MEMORY_SCOPE_AGENT)
#define STC(p,v)  __hip_atomic_store((p), (v), __ATOMIC_RELAXED, __HIP_MEMORY_SCOPE_AGENT)

__device__ __forceinline__ float sigm_(float x){ return 1.0f/(1.0f+expf(-x)); }
__device__ __forceinline__ unsigned rotl_(unsigned x, int r){ return (x<<r)|(x>>(32-r)); }

// Threefry-2x32, 20 rounds, exactly JAX's schedule.
__device__ __forceinline__ void tf2x32_(unsigned k0, unsigned k1, unsigned x0, unsigned x1,
                                        unsigned &o0, unsigned &o1){
  unsigned ks2 = k0 ^ k1 ^ 0x1BD11BDAu;
  x0 += k0; x1 += k1;
  x0+=x1; x1=rotl_(x1,13); x1^=x0;
  x0+=x1; x1=rotl_(x1,15); x1^=x0;
  x0+=x1; x1=rotl_(x1,26); x1^=x0;
  x0+=x1; x1=rotl_(x1, 6); x1^=x0;
  x0+=k1; x1+=ks2+1u;
  x0+=x1; x1=rotl_(x1,17); x1^=x0;
  x0+=x1; x1=rotl_(x1,29); x1^=x0;
  x0+=x1; x1=rotl_(x1,16); x1^=x0;
  x0+=x1; x1=rotl_(x1,24); x1^=x0;
  x0+=ks2; x1+=k0+2u;
  x0+=x1; x1=rotl_(x1,13); x1^=x0;
  x0+=x1; x1=rotl_(x1,15); x1^=x0;
  x0+=x1; x1=rotl_(x1,26); x1^=x0;
  x0+=x1; x1=rotl_(x1, 6); x1^=x0;
  x0+=k0; x1+=k1+3u;
  x0+=x1; x1=rotl_(x1,17); x1^=x0;
  x0+=x1; x1=rotl_(x1,29); x1^=x0;
  x0+=x1; x1=rotl_(x1,16); x1^=x0;
  x0+=x1; x1=rotl_(x1,24); x1^=x0;
  x0+=k1; x1+=ks2+4u;
  x0+=x1; x1=rotl_(x1,13); x1^=x0;
  x0+=x1; x1=rotl_(x1,15); x1^=x0;
  x0+=x1; x1=rotl_(x1,26); x1^=x0;
  x0+=x1; x1=rotl_(x1, 6); x1^=x0;
  x0+=ks2; x1+=k0+5u;
  o0 = x0; o1 = x1;
}

// Gumbel sample + argmax write (shared by both kernels). tid<34 path.
__device__ __forceinline__ void gumbel_emit_(int tid, int bb, int t, float* sZ,
                                             int* yv, int* out){
  if (tid < 34){
    unsigned kk0, kk1; tf2x32_(0u, 42u, 0u, (unsigned)t, kk0, kk1);
    int idx = bb*34 + tid;
    unsigned o0, o1, bits;
#if PARTITIONABLE
    tf2x32_(kk0, kk1, 0u, (unsigned)idx, o0, o1);
    bits = o0 ^ o1;
#else
    if (idx < 1088){ tf2x32_(kk0, kk1, (unsigned)idx, (unsigned)(idx+1088), o0, o1); bits = o0; }
    else           { tf2x32_(kk0, kk1, (unsigned)(idx-1088), (unsigned)idx, o0, o1); bits = o1; }
#endif
    float f = __uint_as_float((bits>>9) | 0x3f800000u) - 1.0f;
    float u = fmaxf(f, 1.17549435e-38f);
    sZ[tid] += -logf(-logf(u));
  }
  __syncthreads();
  if (tid == 0){
    float best = sZ[0]; int bi = 0;
    for (int v2=1; v2<34; v2++){ if (sZ[v2] > best){ best = sZ[v2]; bi = v2; } }
    STC(&yv[bb], bi);
    STC(&out[bb*TT + t], bi);
  }
}

// ============================================================================
// 64-blocks-per-group kernel (grid 512, 2 blocks/CU)
// ============================================================================
__global__ __launch_bounds__(BLKT, 4) void speller_kernel_g64(
    const float* __restrict__ seq, const int* __restrict__ slen,
    const float* __restrict__ Ech, const float* __restrict__ Wkey,
    const float* __restrict__ Wval, const float* __restrict__ bval,
    const float* __restrict__ Wih, const float* __restrict__ Whh,
    const float* __restrict__ bih, const float* __restrict__ bhh,
    const float* __restrict__ Wcdn, const float* __restrict__ bcdn,
    int* __restrict__ out, float* __restrict__ ws, int MS, int CH)
{
  const int tid = threadIdx.x;
  const int bid = blockIdx.x;
  const int grp = bid & 7;         // group ~ XCD round-robin (perf heuristic only)
  const int li  = bid >> 3;        // 0..63

  float* h0   = ws;                          // [64][512]
  float* h1   = h0 + NB*HH;
  float* qt   = h1 + NB*HH;
  float* ctx  = qt + NB*HH;
  float* pm   = ctx + NB*HH;                 // [64][MS]
  float* ps   = pm + NB*MS;
  float* pacc = ps + NB*MS;                  // [64][MS][512]
  int*   iw   = (int*)(pacc + (size_t)NB*MS*HH);
  int*   yv   = iw;                          // [64]
  int*   bar  = iw + 64;                     // [512] zeroed per launch

  // Overlaid phase scratch: A(58.5K) | C(18K) | D(8K) | B(2K)
  __shared__ __align__(16) float smem[24*516 + 2048 + 256];
  __shared__ float sWm[8], sWs[8], sWf[8];
  __shared__ float sAm[32], sAs[32], sAf[32];
  __shared__ float sSc[2];
  __shared__ int   sYv[8], sLen[8], sPref[9], sMap[8];

  float creg = 0.f;   // tid<64: c[b=tid&7][k'=li*8+(tid>>3)]

  int epoch = 0;
  auto gbar = [&](){
    __syncthreads();
    epoch++;
    if (tid == 0){
      int* arr = &bar[grp*64];
      int* rel = &bar[grp*64 + 32];
      int r = __hip_atomic_fetch_add(arr, 1, __ATOMIC_RELAXED, __HIP_MEMORY_SCOPE_AGENT);
      if (r == epoch*64 - 1)
        __hip_atomic_store(rel, epoch, __ATOMIC_RELAXED, __HIP_MEMORY_SCOPE_AGENT);
      else
        while (__hip_atomic_load(rel, __ATOMIC_RELAXED, __HIP_MEMORY_SCOPE_AGENT) < epoch)
          __builtin_amdgcn_s_sleep(1);
    }
    __syncthreads();
  };

  // ---- deterministic LPT batch->group assignment (capacity 8), per-block redundant ----
  if (tid == 0){
    int ln[64]; unsigned char used[64];
    int load[8], cnt[8];
    for (int i=0;i<64;i++){
      int l = slen[i]; if (l<1) l=1; if (l>LL) l=LL;
      ln[i] = l; used[i] = 0;
    }
    for (int g2=0; g2<8; g2++){ load[g2]=0; cnt[g2]=0; }
    for (int it=0; it<64; it++){
      int bi = -1, bl = -1;
      for (int i=0;i<64;i++) if (!used[i] && ln[i] > bl){ bl = ln[i]; bi = i; }
      used[bi] = 1;
      int gi = -1, gl = 0x7fffffff;
      for (int g2=0; g2<8; g2++) if (cnt[g2] < 8 && load[g2] < gl){ gl = load[g2]; gi = g2; }
      if (gi == grp) sMap[cnt[gi]] = bi;
      load[gi] += bl; cnt[gi]++;
    }
  }
  __syncthreads();

  // ---- group-local init ----
  if (li < 8){
    int bb = sMap[li];
    STC(&h0[(size_t)bb*HH + tid], 0.f);
    STC(&h1[(size_t)bb*HH + tid], 0.f);
    STC(&qt[(size_t)bb*HH + tid], 0.f);
  }
  if (li == 0 && tid < 8) STC(&yv[sMap[tid]], 0);   // SOS

  // ================= phases (FP order bit-exact vs verified R10) =================

  // A: gates = Wih*[emb(y); ctx] + Whh*h + (bih+bhh) ; LSTM -> creg, hw
  // Block li owns k' = li*8..li*8+7 for all 4 gates, 8 batches.
  auto phaseA = [&](const float* hr, float* hw){
    float* sX = smem; float* sRed = smem + 24*516; float* sGate = sRed + 2048;
    if (tid < 8) sYv[tid] = LDC(&yv[sMap[tid]]);
    __syncthreads();
    #pragma unroll
    for (int i = 0; i < 24; i++){
      int b = i & 7, s = i >> 3;
      int bb = sMap[b];
      float v;
      if (s == 0)      v = Ech[(size_t)sYv[b]*HH + tid];
      else if (s == 1) v = LDC(&ctx[(size_t)bb*HH + tid]);
      else             v = LDC(&hr[(size_t)bb*HH + tid]);
      sX[i*516 + tid] = v;
    }
    __syncthreads();
    const int w = tid >> 6, lane = tid & 63, rr = lane >> 3, bq = lane & 7;
    float acc[4] = {0.f, 0.f, 0.f, 0.f};
    for (int kt = 0; kt < 12; kt++){
      const int sec = (kt < 4) ? 0 : (kt < 8) ? 1 : 2;
      const int cb4 = (kt & 3) * 128;
      #pragma unroll
      for (int it = 0; it < 4; it++){
        int kkb = w*16 + it*4;            // same 8-wave k-partition as verified A
        const float* xp = &sX[(sec*8 + bq)*516 + cb4 + kkb];
        float x0 = xp[0], x1 = xp[1], x2 = xp[2], x3 = xp[3];
        #pragma unroll
        for (int o = 0; o < 4; o++){
          int j = o*512 + li*8 + rr;
          const float* wp = (kt < 8) ? Wih + (size_t)j*1024 + kt*128 + kkb
                                     : Whh + (size_t)j*512  + (kt-8)*128 + kkb;
          float4 wv = *(const float4*)wp;
          acc[o] += wv.x*x0; acc[o] += wv.y*x1;
          acc[o] += wv.z*x2; acc[o] += wv.w*x3;
        }
      }
    }
    __syncthreads();
    #pragma unroll
    for (int o=0;o<4;o++) sRed[(w*4+o)*64 + lane] = acc[o];
    __syncthreads();
    if (tid < 256){
      int jl = tid >> 3, b2 = tid & 7;      // jl 0..31: gate=jl>>3, kp=jl&7
      int o = jl >> 3, rr2 = jl & 7;
      int j = o*512 + li*8 + rr2;
      float g = bih[j] + bhh[j];
      #pragma unroll
      for (int w2 = 0; w2 < 8; w2++) g += sRed[(w2*4+o)*64 + rr2*8 + b2];
      sGate[jl*8 + b2] = g;
    }
    __syncthreads();
    if (tid < 64){
      int kp = tid >> 3, b3 = tid & 7;
      float gi = sGate[(0*8+kp)*8 + b3];
      float gf = sGate[(1*8+kp)*8 + b3];
      float gg = sGate[(2*8+kp)*8 + b3];
      float go = sGate[(3*8+kp)*8 + b3];
      float cn = sigm_(gf)*creg + sigm_(gi)*tanhf(gg);
      creg = cn;
      STC(&hw[(size_t)sMap[b3]*HH + li*8 + kp], sigm_(go)*tanhf(cn));
    }
  };

  // B: qt[b][col] = sum_k Wkey[k][col]*h[b][k] — 8 blocks/batch, 64 cols each.
  auto phaseB = [&](const float* hw){
    float* sHb = smem;
    int bb = sMap[li >> 3];
    sHb[tid] = LDC(&hw[(size_t)bb*HH + tid]);
    __syncthreads();
    if (tid < 64){
      int col = (li & 7)*64 + tid;
      float a0 = 0.f;
      #pragma unroll 8
      for (int k = 0; k < 512; k++)
        a0 += Wkey[(size_t)k*HH + col] * sHb[k];
      STC(&qt[(size_t)bb*HH + col], a0);
    }
  };

  // C: static chunk ranges over 64 blocks; online-softmax, 8-deep primed prefetch.
  auto phaseC = [&](){
    float* sAcc = smem; float* sQt = smem + 4096;
    if (tid < 8){ int l = slen[sMap[tid]]; if(l<1)l=1; if(l>LL)l=LL; sLen[tid]=l; }
    __syncthreads();
    if (tid == 0){
      sPref[0] = 0;
      for (int i=0;i<8;i++) sPref[i+1] = sPref[i] + (sLen[i]+CH-1)/CH;
    }
    __syncthreads();
    const int gTot = sPref[8];
    const int w = tid >> 6, lane = tid & 63;
    const float SCALE = 1.0f / sqrtf(512.0f);
    const int start = (li*gTot)/64, end = ((li+1)*gTot)/64;
    int b = 0, bLast = -1;
    for (int c = start; c < end; ++c){
      while (sPref[b+1] <= c) b++;
      int slot = c - sPref[b];
      int l0 = slot * CH;
      int lend = min(l0 + CH, sLen[b]);
      int bb = sMap[b];
      if (b != bLast){
        __syncthreads();
        sQt[tid] = LDC(&qt[(size_t)bb*HH + tid]);
        bLast = b;
      }
      __syncthreads();
      const float4* qp = (const float4*)sQt;
      float4 qa = qp[lane], qb = qp[64+lane];
      float m = -FLT_MAX, ss = 0.f;
      float4 aA = make_float4(0,0,0,0), aB = make_float4(0,0,0,0);
      for (int ls = l0; ls < lend; ls += 64){
        float4 ra[8], rb[8];
        #pragma unroll
        for (int d=0; d<8; d++){
          int row = ls + w + d*8;
          if (row < lend){
            const float4* rp = (const float4*)(seq + ((size_t)bb*LL + row)*HH);
            ra[d] = rp[lane]; rb[d] = rp[64+lane];
          }
        }
        #pragma unroll
        for (int d=0; d<8; d++){
          int row = ls + w + d*8;
          if (row < lend){
            float4 ea = ra[d], eb = rb[d];
            float dd = ea.x*qa.x + ea.y*qa.y + ea.z*qa.z + ea.w*qa.w
                     + eb.x*qb.x + eb.y*qb.y + eb.z*qb.z + eb.w*qb.w;
            #pragma unroll
            for (int msk=1; msk<64; msk<<=1) dd += __shfl_xor(dd, msk, 64);
            float sc = dd * SCALE;
            float mn = fmaxf(m, sc);
            float r1 = expf(m - mn);
            float w1 = expf(sc - mn);
            ss = ss*r1 + w1;
            aA.x = aA.x*r1 + w1*ea.x; aA.y = aA.y*r1 + w1*ea.y;
            aA.z = aA.z*r1 + w1*ea.z; aA.w = aA.w*r1 + w1*ea.w;
            aB.x = aB.x*r1 + w1*eb.x; aB.y = aB.y*r1 + w1*eb.y;
            aB.z = aB.z*r1 + w1*eb.z; aB.w = aB.w*r1 + w1*eb.w;
            m = mn;
          }
        }
      }
      ((float4*)(sAcc + w*512))[lane]    = aA;
      ((float4*)(sAcc + w*512))[64+lane] = aB;
      if (lane == 0){ sWm[w] = m; sWs[w] = ss; }
      __syncthreads();
      if (tid == 0){
        float M = sWm[0];
        #pragma unroll
        for (int i=1;i<8;i++) M = fmaxf(M, sWm[i]);
        float S = 0.f;
        #pragma unroll
        for (int i=0;i<8;i++){ float f = expf(sWm[i]-M); sWf[i]=f; S += sWs[i]*f; }
        STC(&pm[bb*MS+slot], M); STC(&ps[bb*MS+slot], S);
      }
      __syncthreads();
      {
        float v = 0.f;
        #pragma unroll
        for (int i=0;i<8;i++) v += sAcc[i*512 + tid] * sWf[i];
        STC(&pacc[((size_t)(bb*MS+slot))*HH + tid], v);
      }
    }
  };

  // D: reduce -> ebar -> ctx ; logits ; gumbel sample. 1 block per batch (li<8).
  auto phaseD = [&](int t, const float* hw){
    if (li < 8){
      float* sEb = smem; float* sHs = smem+512; float* sCt = smem+1024;
      float* sP = smem+1536; float* sZ = smem+1536+272;
      const int bb = sMap[li];
      int ln = sLen[li];
      { int l = slen[bb]; if(l<1)l=1; if(l>LL)l=LL; ln = l; }
      const int nsl = (ln + CH - 1)/CH;
      if (tid < nsl){ sAm[tid] = LDC(&pm[bb*MS + tid]); sAs[tid] = LDC(&ps[bb*MS + tid]); }
      __syncthreads();
      if (tid == 0){
        float M = sAm[0];
        for (int s=1;s<nsl;s++) M = fmaxf(M, sAm[s]);
        float S = 0.f;
        for (int s=0;s<nsl;s++){ float f = expf(sAm[s]-M); sAf[s] = f; S += sAs[s]*f; }
        sSc[0] = S;
      }
      __syncthreads();
      {
        float S = sSc[0];
        float v = 0.f;
        #pragma unroll 8
        for (int s=0;s<nsl;s++) v += LDC(&pacc[((size_t)(bb*MS+s))*HH + tid]) * sAf[s];
        sEb[tid] = v / S;
        sHs[tid] = LDC(&hw[(size_t)bb*HH + tid]);
      }
      __syncthreads();
      {
        const float4* wr = (const float4*)(Wval + (size_t)tid*HH);
        const float4* er = (const float4*)sEb;
        float a = bval[tid];
        #pragma unroll 8
        for (int i=0;i<HH/4;i++){
          float4 w4 = wr[i], e4 = er[i];
          a += w4.x*e4.x; a += w4.y*e4.y; a += w4.z*e4.z; a += w4.w*e4.w;
        }
        sCt[tid] = a;
        STC(&ctx[(size_t)bb*HH + tid], a);
      }
      __syncthreads();
      if (t >= 0){
        if (tid < 34*8){
          int v = tid >> 3, ks = tid & 7;
          const float* wr = Wcdn + (size_t)v*1024 + ks*128;
          const float* xr = (ks < 4) ? (sHs + ks*128) : (sCt + (ks-4)*128);
          float p = 0.f;
          #pragma unroll 8
          for (int i=0;i<128;i++) p += wr[i]*xr[i];
          sP[v*8+ks] = p;
        }
        __syncthreads();
        if (tid < 34){
          float lg = bcdn[tid];
          #pragma unroll
          for (int i=0;i<8;i++) lg += sP[tid*8+i];
          sZ[tid] = lg;
        }
        __syncthreads();
        gumbel_emit_(tid, bb, t, sZ, yv, out);
      }
    }
  };

  // ================= schedule: group-local, 4 group barriers per step =================
  gbar();
  phaseC();                 // qt == 0 -> uniform weights over valid positions
  gbar();
  phaseD(-1, h0);           // ebar/ctx only, no sampling
  gbar();
  for (int t = 0; t < TT; t++){
    const float* hr = (t & 1) ? h1 : h0;
    float* hwv      = (t & 1) ? h0 : h1;
    phaseA(hr, hwv);
    gbar();
    phaseB(hwv);
    gbar();
    phaseC();
    gbar();
    phaseD(t, hwv);
    gbar();
  }
}

// ============================================================================
// Fallback: verified R10 kernel (grid 256, 32 blocks/group), verbatim structure
// ============================================================================
__global__ __launch_bounds__(BLKT, 2) void speller_kernel_g32(
    const float* __restrict__ seq, const int* __restrict__ slen,
    const float* __restrict__ Ech, const float* __restrict__ Wkey,
    const float* __restrict__ Wval, const float* __restrict__ bval,
    const float* __restrict__ Wih, const float* __restrict__ Whh,
    const float* __restrict__ bih, const float* __restrict__ bhh,
    const float* __restrict__ Wcdn, const float* __restrict__ bcdn,
    int* __restrict__ out, float* __restrict__ ws, int MS, int CH)
{
  const int tid = threadIdx.x;
  const int bid = blockIdx.x;
  const int grp = bid & 7;
  const int li  = bid >> 3;
  const int gb0 = grp * 8;

  float* h0   = ws;
  float* h1   = h0 + NB*HH;
  float* qt   = h1 + NB*HH;
  float* ctx  = qt + NB*HH;
  float* pm   = ctx + NB*HH;
  float* ps   = pm + NB*MS;
  float* pacc = ps + NB*MS;
  int*   iw   = (int*)(pacc + (size_t)NB*MS*HH);
  int*   yv   = iw;
  int*   bar  = iw + 64;

  __shared__ float sX[24*516];
  __shared__ float sRed[8*8*64];
  __shared__ float sGate[512];
  __shared__ float sAcc[8*512];
  __shared__ float sQt[512];
  __shared__ float sHb[512];
  __shared__ float sWm[8], sWs[8], sWf[8];
  __shared__ float sEb[512], sHs[512], sCt[512];
  __shared__ float sP[34*8];
  __shared__ float sZ[34];
  __shared__ float sAm[32], sAs[32], sAf[32];
  __shared__ float sSc[2];
  __shared__ int   sYv[8], sLen[8], sPref[9];

  float creg = 0.f;
  int epoch = 0;
  auto gbar = [&](){
    __syncthreads();
    epoch++;
    if (tid == 0){
      int* arr = &bar[grp*64];
      int* rel = &bar[grp*64 + 32];
      int r = __hip_atomic_fetch_add(arr, 1, __ATOMIC_RELAXED, __HIP_MEMORY_SCOPE_AGENT);
      if (r == epoch*32 - 1)
        __hip_atomic_store(rel, epoch, __ATOMIC_RELAXED, __HIP_MEMORY_SCOPE_AGENT);
      else
        while (__hip_atomic_load(rel, __ATOMIC_RELAXED, __HIP_MEMORY_SCOPE_AGENT) < epoch)
          __builtin_amdgcn_s_sleep(1);
    }
    __syncthreads();
  };

  if (li < 8){
    int bb = gb0 + li;
    STC(&h0[bb*HH + tid], 0.f);
    STC(&h1[bb*HH + tid], 0.f);
    STC(&qt[bb*HH + tid], 0.f);
  }
  if (li == 8 && tid < 8) STC(&yv[gb0 + tid], 0);

  auto phaseA = [&](const float* hr, float* hw){
    if (tid < 8) sYv[tid] = LDC(&yv[gb0 + tid]);
    __syncthreads();
    #pragma unroll
    for (int i = 0; i < 24; i++){
      int b = i & 7, s = i >> 3;
      float v;
      if (s == 0)      v = Ech[(size_t)sYv[b]*HH + tid];
      else if (s == 1) v = LDC(&ctx[(gb0+b)*HH + tid]);
      else             v = LDC(&hr[(gb0+b)*HH + tid]);
      sX[i*516 + tid] = v;
    }
    __syncthreads();
    const int w = tid >> 6, lane = tid & 63, rr = lane >> 3, bb = lane & 7;
    float acc[8];
    #pragma unroll
    for (int o=0;o<8;o++) acc[o]=0.f;
    for (int kt = 0; kt < 12; kt++){
      const int sec = (kt < 4) ? 0 : (kt < 8) ? 1 : 2;
      const int cb4 = (kt & 3) * 128;
      #pragma unroll
      for (int it = 0; it < 4; it++){
        int kkb = w*16 + it*4;
        const float* xp = &sX[(sec*8 + bb)*516 + cb4 + kkb];
        float x0 = xp[0], x1 = xp[1], x2 = xp[2], x3 = xp[3];
        #pragma unroll
        for (int o = 0; o < 8; o++){
          int jl = o*8 + rr;
          int j  = (jl >> 4)*512 + li*16 + (jl & 15);
          const float* wp = (kt < 8) ? Wih + (size_t)j*1024 + kt*128 + kkb
                                     : Whh + (size_t)j*512  + (kt-8)*128 + kkb;
          float4 wv = *(const float4*)wp;
          acc[o] += wv.x*x0; acc[o] += wv.y*x1;
          acc[o] += wv.z*x2; acc[o] += wv.w*x3;
        }
      }
    }
    __syncthreads();
    #pragma unroll
    for (int o=0;o<8;o++) sRed[(w*8+o)*64 + lane] = acc[o];
    __syncthreads();
    {
      int jl = tid >> 3, b2 = tid & 7;
      int o = jl >> 3, rr2 = jl & 7;
      int j = (jl >> 4)*512 + li*16 + (jl & 15);
      float g = bih[j] + bhh[j];
      #pragma unroll
      for (int w2 = 0; w2 < 8; w2++) g += sRed[(w2*8+o)*64 + rr2*8 + b2];
      sGate[jl*8 + b2] = g;
    }
    __syncthreads();
    if (tid < 128){
      int kp = tid >> 3, b3 = tid & 7;
      float gi = sGate[(0*16+kp)*8 + b3];
      float gf = sGate[(1*16+kp)*8 + b3];
      float gg = sGate[(2*16+kp)*8 + b3];
      float go = sGate[(3*16+kp)*8 + b3];
      float cn = sigm_(gf)*creg + sigm_(gi)*tanhf(gg);
      creg = cn;
      STC(&hw[(gb0+b3)*HH + li*16 + kp], sigm_(go)*tanhf(cn));
    }
  };

  auto phaseB = [&](const float* hw){
    int bb = gb0 + (li >> 2);
    int c0 = (li & 3) * 128;
    sHb[tid] = LDC(&hw[bb*HH + tid]);
    __syncthreads();
    if (tid < 128){
      int col = c0 + tid;
      float a0 = 0.f;
      #pragma unroll 8
      for (int k = 0; k < 512; k++)
        a0 += Wkey[(size_t)k*HH + col] * sHb[k];
      STC(&qt[bb*HH + col], a0);
    }
  };

  auto phaseC = [&](){
    if (tid < 8){ int l = slen[gb0+tid]; if(l<1)l=1; if(l>LL)l=LL; sLen[tid]=l; }
    __syncthreads();
    if (tid == 0){
      sPref[0] = 0;
      for (int i=0;i<8;i++) sPref[i+1] = sPref[i] + (sLen[i]+CH-1)/CH;
    }
    __syncthreads();
    const int gTot = sPref[8];
    const int w = tid >> 6, lane = tid & 63;
    const float SCALE = 1.0f / sqrtf(512.0f);
    const int start = (li*gTot)/32, end = ((li+1)*gTot)/32;
    int b = 0, bLast = -1;
    for (int c = start; c < end; ++c){
      while (sPref[b+1] <= c) b++;
      int slot = c - sPref[b];
      int l0 = slot * CH;
      int lend = min(l0 + CH, sLen[b]);
      int bb = gb0 + b;
      if (b != bLast){
        __syncthreads();
        sQt[tid] = LDC(&qt[bb*HH + tid]);
        bLast = b;
      }
      __syncthreads();
      const float4* qp = (const float4*)sQt;
      float4 qa = qp[lane], qb = qp[64+lane];
      float m = -FLT_MAX, ss = 0.f;
      float4 aA = make_float4(0,0,0,0), aB = make_float4(0,0,0,0);
      for (int ls = l0; ls < lend; ls += 64){
        float4 ra[8], rb[8];
        #pragma unroll
        for (int d=0; d<8; d++){
          int row = ls + w + d*8;
          if (row < lend){
            const float4* rp = (const float4*)(seq + ((size_t)bb*LL + row)*HH);
            ra[d] = rp[lane]; rb[d] = rp[64+lane];
          }
        }
        #pragma unroll
        for (int d=0; d<8; d++){
          int row = ls + w + d*8;
          if (row < lend){
            float4 ea = ra[d], eb = rb[d];
            float dd = ea.x*qa.x + ea.y*qa.y + ea.z*qa.z + ea.w*qa.w
                     + eb.x*qb.x + eb.y*qb.y + eb.z*qb.z + eb.w*qb.w;
            #pragma unroll
            for (int msk=1; msk<64; msk<<=1) dd += __shfl_xor(dd, msk, 64);
            float sc = dd * SCALE;
            float mn = fmaxf(m, sc);
            float r1 = expf(m - mn);
            float w1 = expf(sc - mn);
            ss = ss*r1 + w1;
            aA.x = aA.x*r1 + w1*ea.x; aA.y = aA.y*r1 + w1*ea.y;
            aA.z = aA.z*r1 + w1*ea.z; aA.w = aA.w*r1 + w1*ea.w;
            aB.x = aB.x*r1 + w1*eb.x; aB.y = aB.y*r1 + w1*eb.y;
            aB.z = aB.z*r1 + w1*eb.z; aB.w = aB.w*r1 + w1*eb.w;
            m = mn;
          }
        }
      }
      ((float4*)(sAcc + w*512))[lane]    = aA;
      ((float4*)(sAcc + w*512))[64+lane] = aB;
      if (lane == 0){ sWm[w] = m; sWs[w] = ss; }
      __syncthreads();
      if (tid == 0){
        float M = sWm[0];
        #pragma unroll
        for (int i=1;i<8;i++) M = fmaxf(M, sWm[i]);
        float S = 0.f;
        #pragma unroll
        for (int i=0;i<8;i++){ float f = expf(sWm[i]-M); sWf[i]=f; S += sWs[i]*f; }
        STC(&pm[bb*MS+slot], M); STC(&ps[bb*MS+slot], S);
      }
      __syncthreads();
      {
        float v = 0.f;
        #pragma unroll
        for (int i=0;i<8;i++) v += sAcc[i*512 + tid] * sWf[i];
        STC(&pacc[((size_t)(bb*MS+slot))*HH + tid], v);
      }
    }
  };

  auto phaseD = [&](int t, const float* hw){
    if (li < 8){
      const int bb = gb0 + li;
      int ln = slen[bb]; if(ln<1)ln=1; if(ln>LL)ln=LL;
      const int nsl = (ln + CH - 1)/CH;
      if (tid < nsl){ sAm[tid] = LDC(&pm[bb*MS + tid]); sAs[tid] = LDC(&ps[bb*MS + tid]); }
      __syncthreads();
      if (tid == 0){
        float M = sAm[0];
        for (int s=1;s<nsl;s++) M = fmaxf(M, sAm[s]);
        float S = 0.f;
        for (int s=0;s<nsl;s++){ float f = expf(sAm[s]-M); sAf[s] = f; S += sAs[s]*f; }
        sSc[0] = S;
      }
      __syncthreads();
      {
        float S = sSc[0];
        float v = 0.f;
        #pragma unroll 8
        for (int s=0;s<nsl;s++) v += LDC(&pacc[((size_t)(bb*MS+s))*HH + tid]) * sAf[s];
        sEb[tid] = v / S;
        sHs[tid] = LDC(&hw[bb*HH + tid]);
      }
      __syncthreads();
      {
        const float4* wr = (const float4*)(Wval + (size_t)tid*HH);
        const float4* er = (const float4*)sEb;
        float a = bval[tid];
        #pragma unroll 8
        for (int i=0;i<HH/4;i++){
          float4 w4 = wr[i], e4 = er[i];
          a += w4.x*e4.x; a += w4.y*e4.y; a += w4.z*e4.z; a += w4.w*e4.w;
        }
        sCt[tid] = a;
        STC(&ctx[bb*HH + tid], a);
      }
      __syncthreads();
      if (t >= 0){
        if (tid < 34*8){
          int v = tid >> 3, ks = tid & 7;
          const float* wr = Wcdn + (size_t)v*1024 + ks*128;
          const float* xr = (ks < 4) ? (sHs + ks*128) : (sCt + (ks-4)*128);
          float p = 0.f;
          #pragma unroll 8
          for (int i=0;i<128;i++) p += wr[i]*xr[i];
          sP[v*8+ks] = p;
        }
        __syncthreads();
        if (tid < 34){
          float lg = bcdn[tid];
          #pragma unroll
          for (int i=0;i<8;i++) lg += sP[tid*8+i];
          sZ[tid] = lg;
        }
        __syncthreads();
        gumbel_emit_(tid, bb, t, sZ, yv, out);
      }
    }
  };

  gbar();
  phaseC();
  gbar();
  phaseD(-1, h0);
  gbar();
  for (int t = 0; t < TT; t++){
    const float* hr = (t & 1) ? h1 : h0;
    float* hwv      = (t & 1) ? h0 : h1;
    phaseA(hr, hwv);
    gbar();
    phaseB(hwv);
    gbar();
    phaseC();
    gbar();
    phaseD(t, hwv);
    gbar();
  }
}

extern "C" void kernel_launch(void* const* d_in, const int* in_sizes, int n_in,
                              void* d_out, int out_size, void* d_ws, size_t ws_size,
                              hipStream_t stream)
{
  const float* seq  = (const float*)d_in[0];
  const int*   slen = (const int*)d_in[1];
  const float* Ech  = (const float*)d_in[2];
  const float* Wkey = (const float*)d_in[3];
  // d_in[4] = b_key: cancels inside softmax, unused.
  const float* Wval = (const float*)d_in[5];
  const float* bval = (const float*)d_in[6];
  const float* Wih  = (const float*)d_in[7];
  const float* Whh  = (const float*)d_in[8];
  const float* bih  = (const float*)d_in[9];
  const float* bhh  = (const float*)d_in[10];
  const float* Wcdn = (const float*)d_in[11];
  const float* bcdn = (const float*)d_in[12];
  int*   out = (int*)d_out;
  float* ws  = (float*)d_ws;

  int MS = 32;
  size_t floats_total;
  while (true){
    floats_total = 4*(size_t)NB*HH + (size_t)NB*MS*(2 + HH);
    size_t need = (floats_total + 1024)*4;
    if (need <= ws_size || MS == 1) break;
    MS >>= 1;
  }
  int CH = 2048 / MS;

  size_t bar_off = (floats_total + 64)*4;
  hipMemsetAsync((char*)d_ws + bar_off, 0, 512*4, stream);

  void* args[] = { (void*)&seq, (void*)&slen, (void*)&Ech, (void*)&Wkey,
                   (void*)&Wval, (void*)&bval, (void*)&Wih, (void*)&Whh,
                   (void*)&bih, (void*)&bhh, (void*)&Wcdn, (void*)&bcdn,
                   (void*)&out, (void*)&ws, (void*)&MS, (void*)&CH };

  int occ = 0;
  hipError_t qe = hipOccupancyMaxActiveBlocksPerMultiprocessor(
      &occ, (const void*)speller_kernel_g64, BLKT, 0);
  if (qe == hipSuccess && occ >= 2){
    hipLaunchCooperativeKernel((void*)speller_kernel_g64, dim3(512), dim3(BLKT),
                               args, 0, stream);
  } else {
    hipLaunchCooperativeKernel((void*)speller_kernel_g32, dim3(256), dim3(BLKT),
                               args, 0, stream);
  }
}

// Round 13
// 77865.533 us; speedup vs baseline: 1.7219x; 1.0619x over previous
//
#include <hip/hip_runtime.h>
#include <cstdint>
#include <cfloat>
#include <cmath>

#define NB 64
#define LL 2048
#define HH 512
#define VV 34
#define TT 600
#define BLKT 512
#define GRID 256
#define GBLK 32     // blocks per group

// JAX threefry_partitionable (default since jax 0.4.36): bits = o0 ^ o1. VERIFIED round 2.
#define PARTITIONABLE 1

// Coherence-point (cross-XCD-safe) data path: bypasses L1/L2; no fences needed.
#define LDC(p)    __hip_atomic_load((p), __ATOMIC_RELAXED, __HIP_MEMORY_SCOPE_AGENT)
#define STC(p,v)  __hip_atomic_store((p), (v), __ATOMIC_RELAXED, __HIP_MEMORY_SCOPE_AGENT)

__device__ __forceinline__ float sigm_(float x){ return 1.0f/(1.0f+expf(-x)); }
__device__ __forceinline__ unsigned rotl_(unsigned x, int r){ return (x<<r)|(x>>(32-r)); }

// Threefry-2x32, 20 rounds, exactly JAX's schedule.
__device__ __forceinline__ void tf2x32_(unsigned k0, unsigned k1, unsigned x0, unsigned x1,
                                        unsigned &o0, unsigned &o1){
  unsigned ks2 = k0 ^ k1 ^ 0x1BD11BDAu;
  x0 += k0; x1 += k1;
  x0+=x1; x1=rotl_(x1,13); x1^=x0;
  x0+=x1; x1=rotl_(x1,15); x1^=x0;
  x0+=x1; x1=rotl_(x1,26); x1^=x0;
  x0+=x1; x1=rotl_(x1, 6); x1^=x0;
  x0+=k1; x1+=ks2+1u;
  x0+=x1; x1=rotl_(x1,17); x1^=x0;
  x0+=x1; x1=rotl_(x1,29); x1^=x0;
  x0+=x1; x1=rotl_(x1,16); x1^=x0;
  x0+=x1; x1=rotl_(x1,24); x1^=x0;
  x0+=ks2; x1+=k0+2u;
  x0+=x1; x1=rotl_(x1,13); x1^=x0;
  x0+=x1; x1=rotl_(x1,15); x1^=x0;
  x0+=x1; x1=rotl_(x1,26); x1^=x0;
  x0+=x1; x1=rotl_(x1, 6); x1^=x0;
  x0+=k0; x1+=k1+3u;
  x0+=x1; x1=rotl_(x1,17); x1^=x0;
  x0+=x1; x1=rotl_(x1,29); x1^=x0;
  x0+=x1; x1=rotl_(x1,16); x1^=x0;
  x0+=x1; x1=rotl_(x1,24); x1^=x0;
  x0+=k1; x1+=ks2+4u;
  x0+=x1; x1=rotl_(x1,13); x1^=x0;
  x0+=x1; x1=rotl_(x1,15); x1^=x0;
  x0+=x1; x1=rotl_(x1,26); x1^=x0;
  x0+=x1; x1=rotl_(x1, 6); x1^=x0;
  x0+=ks2; x1+=k0+5u;
  o0 = x0; o1 = x1;
}

// Gumbel sample + argmax write. tid<34 path.
__device__ __forceinline__ void gumbel_emit_(int tid, int bb, int t, float* sZ,
                                             int* yv, int* out){
  if (tid < 34){
    unsigned kk0, kk1; tf2x32_(0u, 42u, 0u, (unsigned)t, kk0, kk1);
    int idx = bb*34 + tid;
    unsigned o0, o1, bits;
#if PARTITIONABLE
    tf2x32_(kk0, kk1, 0u, (unsigned)idx, o0, o1);
    bits = o0 ^ o1;
#else
    if (idx < 1088){ tf2x32_(kk0, kk1, (unsigned)idx, (unsigned)(idx+1088), o0, o1); bits = o0; }
    else           { tf2x32_(kk0, kk1, (unsigned)(idx-1088), (unsigned)idx, o0, o1); bits = o1; }
#endif
    float f = __uint_as_float((bits>>9) | 0x3f800000u) - 1.0f;
    float u = fmaxf(f, 1.17549435e-38f);
    sZ[tid] += -logf(-logf(u));
  }
  __syncthreads();
  if (tid == 0){
    float best = sZ[0]; int bi = 0;
    for (int v2=1; v2<34; v2++){ if (sZ[v2] > best){ best = sZ[v2]; bi = v2; } }
    STC(&yv[bb], bi);
    STC(&out[bb*TT + t], bi);
  }
}

// ============================================================================
// Verified R10 kernel (grid 256, 32 blocks/group) + LPT batch->group remap
// ============================================================================
__global__ __launch_bounds__(BLKT, 2) void speller_kernel_g32(
    const float* __restrict__ seq, const int* __restrict__ slen,
    const float* __restrict__ Ech, const float* __restrict__ Wkey,
    const float* __restrict__ Wval, const float* __restrict__ bval,
    const float* __restrict__ Wih, const float* __restrict__ Whh,
    const float* __restrict__ bih, const float* __restrict__ bhh,
    const float* __restrict__ Wcdn, const float* __restrict__ bcdn,
    int* __restrict__ out, float* __restrict__ ws, int MS, int CH)
{
  const int tid = threadIdx.x;
  const int bid = blockIdx.x;
  const int grp = bid & 7;         // group ~ XCD round-robin (perf heuristic only)
  const int li  = bid >> 3;        // 0..31

  float* h0   = ws;
  float* h1   = h0 + NB*HH;
  float* qt   = h1 + NB*HH;
  float* ctx  = qt + NB*HH;
  float* pm   = ctx + NB*HH;
  float* ps   = pm + NB*MS;
  float* pacc = ps + NB*MS;
  int*   iw   = (int*)(pacc + (size_t)NB*MS*HH);
  int*   yv   = iw;
  int*   bar  = iw + 64;

  __shared__ float sX[24*516];
  __shared__ float sRed[8*8*64];
  __shared__ float sGate[512];
  __shared__ float sAcc[8*512];
  __shared__ float sQt[512];
  __shared__ float sHb[512];
  __shared__ float sWm[8], sWs[8], sWf[8];
  __shared__ float sEb[512], sHs[512], sCt[512];
  __shared__ float sP[34*8];
  __shared__ float sZ[34];
  __shared__ float sAm[32], sAs[32], sAf[32];
  __shared__ float sSc[2];
  __shared__ int   sYv[8], sLen[8], sPref[9], sMap[8];

  float creg = 0.f;
  int epoch = 0;
  auto gbar = [&](){
    __syncthreads();
    epoch++;
    if (tid == 0){
      int* arr = &bar[grp*64];
      int* rel = &bar[grp*64 + 32];
      int r = __hip_atomic_fetch_add(arr, 1, __ATOMIC_RELAXED, __HIP_MEMORY_SCOPE_AGENT);
      if (r == epoch*GBLK - 1)
        __hip_atomic_store(rel, epoch, __ATOMIC_RELAXED, __HIP_MEMORY_SCOPE_AGENT);
      else
        while (__hip_atomic_load(rel, __ATOMIC_RELAXED, __HIP_MEMORY_SCOPE_AGENT) < epoch)
          __builtin_amdgcn_s_sleep(1);
    }
    __syncthreads();
  };

  // ---- deterministic LPT batch->group assignment (capacity 8), per-block redundant ----
  if (tid == 0){
    int ln[64]; unsigned char used[64];
    int load[8], cnt[8];
    for (int i=0;i<64;i++){
      int l = slen[i]; if (l<1) l=1; if (l>LL) l=LL;
      ln[i] = l; used[i] = 0;
    }
    for (int g2=0; g2<8; g2++){ load[g2]=0; cnt[g2]=0; }
    for (int it=0; it<64; it++){
      int bi = -1, bl = -1;
      for (int i=0;i<64;i++) if (!used[i] && ln[i] > bl){ bl = ln[i]; bi = i; }
      used[bi] = 1;
      int gi = -1, gl = 0x7fffffff;
      for (int g2=0; g2<8; g2++) if (cnt[g2] < 8 && load[g2] < gl){ gl = load[g2]; gi = g2; }
      if (gi == grp) sMap[cnt[gi]] = bi;
      load[gi] += bl; cnt[gi]++;
    }
  }
  __syncthreads();

  // ---- group-local init ----
  if (li < 8){
    int bb = sMap[li];
    STC(&h0[(size_t)bb*HH + tid], 0.f);
    STC(&h1[(size_t)bb*HH + tid], 0.f);
    STC(&qt[(size_t)bb*HH + tid], 0.f);
  }
  if (li == 8 && tid < 8) STC(&yv[sMap[tid]], 0);   // SOS

  // ================= phases (FP order bit-exact vs verified R10) =================

  auto phaseA = [&](const float* hr, float* hw){
    if (tid < 8) sYv[tid] = LDC(&yv[sMap[tid]]);
    __syncthreads();
    #pragma unroll
    for (int i = 0; i < 24; i++){
      int b = i & 7, s = i >> 3;
      int bb = sMap[b];
      float v;
      if (s == 0)      v = Ech[(size_t)sYv[b]*HH + tid];
      else if (s == 1) v = LDC(&ctx[(size_t)bb*HH + tid]);
      else             v = LDC(&hr[(size_t)bb*HH + tid]);
      sX[i*516 + tid] = v;
    }
    __syncthreads();
    const int w = tid >> 6, lane = tid & 63, rr = lane >> 3, bb = lane & 7;
    float acc[8];
    #pragma unroll
    for (int o=0;o<8;o++) acc[o]=0.f;
    for (int kt = 0; kt < 12; kt++){
      const int sec = (kt < 4) ? 0 : (kt < 8) ? 1 : 2;
      const int cb4 = (kt & 3) * 128;
      #pragma unroll
      for (int it = 0; it < 4; it++){
        int kkb = w*16 + it*4;
        const float* xp = &sX[(sec*8 + bb)*516 + cb4 + kkb];
        float x0 = xp[0], x1 = xp[1], x2 = xp[2], x3 = xp[3];
        #pragma unroll
        for (int o = 0; o < 8; o++){
          int jl = o*8 + rr;
          int j  = (jl >> 4)*512 + li*16 + (jl & 15);
          const float* wp = (kt < 8) ? Wih + (size_t)j*1024 + kt*128 + kkb
                                     : Whh + (size_t)j*512  + (kt-8)*128 + kkb;
          float4 wv = *(const float4*)wp;
          acc[o] += wv.x*x0; acc[o] += wv.y*x1;
          acc[o] += wv.z*x2; acc[o] += wv.w*x3;
        }
      }
    }
    __syncthreads();
    #pragma unroll
    for (int o=0;o<8;o++) sRed[(w*8+o)*64 + lane] = acc[o];
    __syncthreads();
    {
      int jl = tid >> 3, b2 = tid & 7;
      int o = jl >> 3, rr2 = jl & 7;
      int j = (jl >> 4)*512 + li*16 + (jl & 15);
      float g = bih[j] + bhh[j];
      #pragma unroll
      for (int w2 = 0; w2 < 8; w2++) g += sRed[(w2*8+o)*64 + rr2*8 + b2];
      sGate[jl*8 + b2] = g;
    }
    __syncthreads();
    if (tid < 128){
      int kp = tid >> 3, b3 = tid & 7;
      float gi = sGate[(0*16+kp)*8 + b3];
      float gf = sGate[(1*16+kp)*8 + b3];
      float gg = sGate[(2*16+kp)*8 + b3];
      float go = sGate[(3*16+kp)*8 + b3];
      float cn = sigm_(gf)*creg + sigm_(gi)*tanhf(gg);
      creg = cn;
      STC(&hw[(size_t)sMap[b3]*HH + li*16 + kp], sigm_(go)*tanhf(cn));
    }
  };

  auto phaseB = [&](const float* hw){
    int bb = sMap[li >> 2];
    int c0 = (li & 3) * 128;
    sHb[tid] = LDC(&hw[(size_t)bb*HH + tid]);
    __syncthreads();
    if (tid < 128){
      int col = c0 + tid;
      float a0 = 0.f;
      #pragma unroll 8
      for (int k = 0; k < 512; k++)
        a0 += Wkey[(size_t)k*HH + col] * sHb[k];
      STC(&qt[(size_t)bb*HH + col], a0);
    }
  };

  auto phaseC = [&](){
    if (tid < 8){ int l = slen[sMap[tid]]; if(l<1)l=1; if(l>LL)l=LL; sLen[tid]=l; }
    __syncthreads();
    if (tid == 0){
      sPref[0] = 0;
      for (int i=0;i<8;i++) sPref[i+1] = sPref[i] + (sLen[i]+CH-1)/CH;
    }
    __syncthreads();
    const int gTot = sPref[8];
    const int w = tid >> 6, lane = tid & 63;
    const float SCALE = 1.0f / sqrtf(512.0f);
    const int start = (li*gTot)/GBLK, end = ((li+1)*gTot)/GBLK;
    int b = 0, bLast = -1;
    for (int c = start; c < end; ++c){
      while (sPref[b+1] <= c) b++;
      int slot = c - sPref[b];
      int l0 = slot * CH;
      int lend = min(l0 + CH, sLen[b]);
      int bb = sMap[b];
      if (b != bLast){
        __syncthreads();
        sQt[tid] = LDC(&qt[(size_t)bb*HH + tid]);
        bLast = b;
      }
      __syncthreads();
      const float4* qp = (const float4*)sQt;
      float4 qa = qp[lane], qb = qp[64+lane];
      float m = -FLT_MAX, ss = 0.f;
      float4 aA = make_float4(0,0,0,0), aB = make_float4(0,0,0,0);
      for (int ls = l0; ls < lend; ls += 64){
        float4 ra[8], rb[8];
        #pragma unroll
        for (int d=0; d<8; d++){
          int row = ls + w + d*8;
          if (row < lend){
            const float4* rp = (const float4*)(seq + ((size_t)bb*LL + row)*HH);
            ra[d] = rp[lane]; rb[d] = rp[64+lane];
          }
        }
        #pragma unroll
        for (int d=0; d<8; d++){
          int row = ls + w + d*8;
          if (row < lend){
            float4 ea = ra[d], eb = rb[d];
            float dd = ea.x*qa.x + ea.y*qa.y + ea.z*qa.z + ea.w*qa.w
                     + eb.x*qb.x + eb.y*qb.y + eb.z*qb.z + eb.w*qb.w;
            #pragma unroll
            for (int msk=1; msk<64; msk<<=1) dd += __shfl_xor(dd, msk, 64);
            float sc = dd * SCALE;
            float mn = fmaxf(m, sc);
            float r1 = expf(m - mn);
            float w1 = expf(sc - mn);
            ss = ss*r1 + w1;
            aA.x = aA.x*r1 + w1*ea.x; aA.y = aA.y*r1 + w1*ea.y;
            aA.z = aA.z*r1 + w1*ea.z; aA.w = aA.w*r1 + w1*ea.w;
            aB.x = aB.x*r1 + w1*eb.x; aB.y = aB.y*r1 + w1*eb.y;
            aB.z = aB.z*r1 + w1*eb.z; aB.w = aB.w*r1 + w1*eb.w;
            m = mn;
          }
        }
      }
      ((float4*)(sAcc + w*512))[lane]    = aA;
      ((float4*)(sAcc + w*512))[64+lane] = aB;
      if (lane == 0){ sWm[w] = m; sWs[w] = ss; }
      __syncthreads();
      if (tid == 0){
        float M = sWm[0];
        #pragma unroll
        for (int i=1;i<8;i++) M = fmaxf(M, sWm[i]);
        float S = 0.f;
        #pragma unroll
        for (int i=0;i<8;i++){ float f = expf(sWm[i]-M); sWf[i]=f; S += sWs[i]*f; }
        STC(&pm[bb*MS+slot], M); STC(&ps[bb*MS+slot], S);
      }
      __syncthreads();
      {
        float v = 0.f;
        #pragma unroll
        for (int i=0;i<8;i++) v += sAcc[i*512 + tid] * sWf[i];
        STC(&pacc[((size_t)(bb*MS+slot))*HH + tid], v);
      }
    }
  };

  auto phaseD = [&](int t, const float* hw){
    if (li < 8){
      const int bb = sMap[li];
      int ln = slen[bb]; if(ln<1)ln=1; if(ln>LL)ln=LL;
      const int nsl = (ln + CH - 1)/CH;
      if (tid < nsl){ sAm[tid] = LDC(&pm[bb*MS + tid]); sAs[tid] = LDC(&ps[bb*MS + tid]); }
      __syncthreads();
      if (tid == 0){
        float M = sAm[0];
        for (int s=1;s<nsl;s++) M = fmaxf(M, sAm[s]);
        float S = 0.f;
        for (int s=0;s<nsl;s++){ float f = expf(sAm[s]-M); sAf[s] = f; S += sAs[s]*f; }
        sSc[0] = S;
      }
      __syncthreads();
      {
        float S = sSc[0];
        float v = 0.f;
        #pragma unroll 8
        for (int s=0;s<nsl;s++) v += LDC(&pacc[((size_t)(bb*MS+s))*HH + tid]) * sAf[s];
        sEb[tid] = v / S;
        sHs[tid] = LDC(&hw[(size_t)bb*HH + tid]);
      }
      __syncthreads();
      {
        const float4* wr = (const float4*)(Wval + (size_t)tid*HH);
        const float4* er = (const float4*)sEb;
        float a = bval[tid];
        #pragma unroll 8
        for (int i=0;i<HH/4;i++){
          float4 w4 = wr[i], e4 = er[i];
          a += w4.x*e4.x; a += w4.y*e4.y; a += w4.z*e4.z; a += w4.w*e4.w;
        }
        sCt[tid] = a;
        STC(&ctx[(size_t)bb*HH + tid], a);
      }
      __syncthreads();
      if (t >= 0){
        if (tid < 34*8){
          int v = tid >> 3, ks = tid & 7;
          const float* wr = Wcdn + (size_t)v*1024 + ks*128;
          const float* xr = (ks < 4) ? (sHs + ks*128) : (sCt + (ks-4)*128);
          float p = 0.f;
          #pragma unroll 8
          for (int i=0;i<128;i++) p += wr[i]*xr[i];
          sP[v*8+ks] = p;
        }
        __syncthreads();
        if (tid < 34){
          float lg = bcdn[tid];
          #pragma unroll
          for (int i=0;i<8;i++) lg += sP[tid*8+i];
          sZ[tid] = lg;
        }
        __syncthreads();
        gumbel_emit_(tid, bb, t, sZ, yv, out);
      }
    }
  };

  // ================= schedule: group-local, 4 group barriers per step =================
  gbar();
  phaseC();                 // qt == 0 -> uniform weights over valid positions
  gbar();
  phaseD(-1, h0);           // ebar/ctx only, no sampling
  gbar();
  for (int t = 0; t < TT; t++){
    const float* hr = (t & 1) ? h1 : h0;
    float* hwv      = (t & 1) ? h0 : h1;
    phaseA(hr, hwv);
    gbar();
    phaseB(hwv);
    gbar();
    phaseC();
    gbar();
    phaseD(t, hwv);
    gbar();
  }
}

extern "C" void kernel_launch(void* const* d_in, const int* in_sizes, int n_in,
                              void* d_out, int out_size, void* d_ws, size_t ws_size,
                              hipStream_t stream)
{
  const float* seq  = (const float*)d_in[0];
  const int*   slen = (const int*)d_in[1];
  const float* Ech  = (const float*)d_in[2];
  const float* Wkey = (const float*)d_in[3];
  // d_in[4] = b_key: cancels inside softmax, unused.
  const float* Wval = (const float*)d_in[5];
  const float* bval = (const float*)d_in[6];
  const float* Wih  = (const float*)d_in[7];
  const float* Whh  = (const float*)d_in[8];
  const float* bih  = (const float*)d_in[9];
  const float* bhh  = (const float*)d_in[10];
  const float* Wcdn = (const float*)d_in[11];
  const float* bcdn = (const float*)d_in[12];
  int*   out = (int*)d_out;
  float* ws  = (float*)d_ws;

  int MS = 32;
  size_t floats_total;
  while (true){
    floats_total = 4*(size_t)NB*HH + (size_t)NB*MS*(2 + HH);
    size_t need = (floats_total + 1024)*4;
    if (need <= ws_size || MS == 1) break;
    MS >>= 1;
  }
  int CH = 2048 / MS;

  size_t bar_off = (floats_total + 64)*4;
  hipMemsetAsync((char*)d_ws + bar_off, 0, 512*4, stream);

  void* args[] = { (void*)&seq, (void*)&slen, (void*)&Ech, (void*)&Wkey,
                   (void*)&Wval, (void*)&bval, (void*)&Wih, (void*)&Whh,
                   (void*)&bih, (void*)&bhh, (void*)&Wcdn, (void*)&bcdn,
                   (void*)&out, (void*)&ws, (void*)&MS, (void*)&CH };

  hipLaunchCooperativeKernel((void*)speller_kernel_g32, dim3(GRID), dim3(BLKT),
                             args, 0, stream);
}